// Round 7
// baseline (184.765 us; speedup 1.0000x reference)
//
#include <hip/hip_runtime.h>
#include <math.h>

// ---------------------------------------------------------------------------
// Types / helpers
// ---------------------------------------------------------------------------
typedef short bf16x8 __attribute__((ext_vector_type(8)));   // 8 bf16 (4 VGPRs)
typedef float f32x4  __attribute__((ext_vector_type(4)));

#define MFMA16 __builtin_amdgcn_mfma_f32_16x16x32_bf16
#define LOG2E 1.4426950408889634f

static __device__ __forceinline__ short f2bf(float f) {
  union { float f; unsigned u; } x; x.f = f;
  unsigned r = (x.u + 0x7FFFu + ((x.u >> 16) & 1u)) >> 16;  // RTNE
  return (short)r;
}
static __device__ __forceinline__ unsigned packbf(float a, float b) {
  return (unsigned)(unsigned short)f2bf(a) | ((unsigned)(unsigned short)f2bf(b) << 16);
}
static __device__ __forceinline__ float bf2f(short s) {
  union { unsigned u; float f; } x; x.u = ((unsigned)(unsigned short)s) << 16;
  return x.f;
}
static __device__ __forceinline__ void gload_lds16(const void* g, void* l) {
  __builtin_amdgcn_global_load_lds((const __attribute__((address_space(1))) void*)g,
                                   (__attribute__((address_space(3))) void*)l, 16, 0, 0);
}
static __device__ __forceinline__ float ex2(float x) {
  float r; asm("v_exp_f32 %0, %1" : "=v"(r) : "v"(x)); return r;
}
static __device__ __forceinline__ float rcpf(float x) {
  float r; asm("v_rcp_f32 %0, %1" : "=v"(r) : "v"(x)); return r;
}
static __device__ __forceinline__ unsigned cvtpk(float lo, float hi) {
  unsigned r; asm("v_cvt_pk_bf16_f32 %0, %1, %2" : "=v"(r) : "v"(lo), "v"(hi));
  return r;
}

// ---------------------------------------------------------------------------
// Transpose one 32x32 tile: fp32 in [K][N] -> bf16 out [N][K]
// ---------------------------------------------------------------------------
__device__ __forceinline__ void tr_tile(
    const float* __restrict__ in, short* __restrict__ out,
    int K, int N, int nt, int kt, float (*t)[33])
{
  int n0 = nt * 32, k0 = kt * 32;
  int tx = threadIdx.x & 31, ty = threadIdx.x >> 5;
  #pragma unroll
  for (int i = 0; i < 4; ++i)
    t[ty + 8 * i][tx] = in[(size_t)(k0 + ty + 8 * i) * N + n0 + tx];
  __syncthreads();
  #pragma unroll
  for (int i = 0; i < 4; ++i)
    out[(size_t)(n0 + ty + 8 * i) * K + k0 + tx] = f2bf(t[tx][ty + 8 * i]);
}

// Fused prep: Wq/Wk/Wv/WA/WB transposes + x fp32->bf16 convert. grid 10368.
__global__ __launch_bounds__(256) void prep_kernel(
    const float* __restrict__ x, const float* __restrict__ Wq,
    const float* __restrict__ Wk, const float* __restrict__ Wv,
    const float* __restrict__ WA, const float* __restrict__ WB,
    short* __restrict__ xb, short* __restrict__ Wqt, short* __restrict__ Wkt,
    short* __restrict__ Wvt, short* __restrict__ WABt)
{
  __shared__ float t[32][33];
  int b = blockIdx.x;
  if (b < 4096)       tr_tile(Wq, Wqt, 2048, 2048, b & 63, b >> 6, t);
  else if (b < 5120)  { int c = b - 4096; tr_tile(Wk, Wkt, 2048, 512, c & 15, c >> 4, t); }
  else if (b < 6144)  { int c = b - 5120; tr_tile(Wv, Wvt, 2048, 512, c & 15, c >> 4, t); }
  else if (b < 6208)  { int c = b - 6144; tr_tile(WA, WABt, 2048, 32, 0, c, t); }
  else if (b < 6272)  { int c = b - 6208; tr_tile(WB, WABt + 32 * 2048, 2048, 32, 0, c, t); }
  else {
    int i = (b - 6272) * 256 + threadIdx.x;          // 4096 blocks, 1M float4
    float4 v = ((const float4*)x)[i];
    short4 o; o.x = f2bf(v.x); o.y = f2bf(v.y); o.z = f2bf(v.z); o.w = f2bf(v.w);
    ((short4*)xb)[i] = o;
  }
}

// Fused mid: Wo transpose + RoPE on Q/K. grid 4096 + 10240 = 14336.
__global__ __launch_bounds__(256) void mid_kernel(
    const float* __restrict__ Wo, short* __restrict__ Wot,
    short* __restrict__ Q, short* __restrict__ K)
{
  __shared__ float t[32][33];
  int b = blockIdx.x;
  if (b < 4096) { tr_tile(Wo, Wot, 2048, 2048, b & 63, b >> 6, t); return; }
  int idx = (b - 4096) * 256 + threadIdx.x;   // < 2048*20*64
  int d  = idx & 63;
  int hh = (idx >> 6) % 20;
  int tt = idx / (20 * 64);
  short* base = (hh < 16) ? Q + (size_t)tt * 2048 + hh * 128 + d
                          : K + (size_t)tt * 512 + (hh - 16) * 128 + d;
  float inv = __expf((float)d * -0.14391156831212789f);  // 10000^(-d/64)
  float ang = (float)tt * inv;
  float sn, cs;
  __sincosf(ang, &sn, &cs);
  float x1 = bf2f(base[0]), x2 = bf2f(base[64]);
  base[0]  = f2bf(x1 * cs - x2 * sn);
  base[64] = f2bf(x2 * cs + x1 * sn);
}

// ---------------------------------------------------------------------------
// bf16 MFMA GEMM core, 2-phase LDS double-buffer: stage(k+1) issued before
// compute(k); single vmcnt(0)+barrier per K-step (staging latency covered by
// one full compute phase). C128x128, BK=32, A [M][K], Bt [N][K] bf16.
// ---------------------------------------------------------------------------
__device__ __forceinline__ void gemm128_core(
    const short* __restrict__ A, const short* __restrict__ Bt,
    int m0, int n0, int Kd, short (*Asm)[4096], short (*Bsm)[4096],
    f32x4 acc[4][4])
{
  const int tid = threadIdx.x;
  const int lane = tid & 63, w = tid >> 6;
  const int lr = lane & 15, g4 = lane >> 4;
  const int wm = w >> 1, wn = w & 1;

  // prologue: stage k0=0 into buf0
  #pragma unroll
  for (int s = 0; s < 2; ++s) {
    int c = (s * 4 + w) * 64 + lane;
    int row = c >> 2, q = c & 3;
    gload_lds16(A  + (size_t)(m0 + row) * Kd + q * 8, Asm[0] + c * 8);
    gload_lds16(Bt + (size_t)(n0 + row) * Kd + q * 8, Bsm[0] + c * 8);
  }
  asm volatile("s_waitcnt vmcnt(0)" ::: "memory");
  __builtin_amdgcn_s_barrier();

  for (int k0 = 0; k0 < Kd; k0 += 32) {
    const int b = (k0 >> 5) & 1;
    const bool pf = (k0 + 32 < Kd);
    if (pf) {
      #pragma unroll
      for (int s = 0; s < 2; ++s) {
        int c = (s * 4 + w) * 64 + lane;
        int row = c >> 2, q = c & 3;
        gload_lds16(A  + (size_t)(m0 + row) * Kd + k0 + 32 + q * 8,
                    Asm[b ^ 1] + c * 8);
        gload_lds16(Bt + (size_t)(n0 + row) * Kd + k0 + 32 + q * 8,
                    Bsm[b ^ 1] + c * 8);
      }
    }
    bf16x8 af[4], bff[4];
    #pragma unroll
    for (int mi = 0; mi < 4; ++mi)
      af[mi] = *(const bf16x8*)(Asm[b] + (wm * 64 + mi * 16 + lr) * 32 + g4 * 8);
    #pragma unroll
    for (int ni = 0; ni < 4; ++ni)
      bff[ni] = *(const bf16x8*)(Bsm[b] + (wn * 64 + ni * 16 + lr) * 32 + g4 * 8);
    #pragma unroll
    for (int mi = 0; mi < 4; ++mi)
      #pragma unroll
      for (int ni = 0; ni < 4; ++ni)
        acc[mi][ni] = MFMA16(af[mi], bff[ni], acc[mi][ni], 0, 0, 0);
    asm volatile("s_waitcnt vmcnt(0) lgkmcnt(0)" ::: "memory");
    __builtin_amdgcn_s_barrier();
  }
}

// Fused QKV + low-rank AB projection. grid (25, 16).
// A-projection (mode 3, cols 0-31) pre-scaled by log2(e) for exp2-domain attn.
__global__ __launch_bounds__(256, 3) void gemm_qkv_kernel(
    const short* __restrict__ xb, const short* __restrict__ Wqt,
    const short* __restrict__ Wkt, const short* __restrict__ Wvt,
    const short* __restrict__ WABt,
    short* __restrict__ Qb, short* __restrict__ Kb, short* __restrict__ Vtb,
    short* __restrict__ Ab, short* __restrict__ Bb)
{
  __shared__ __align__(16) short Asm[2][4096];
  __shared__ __align__(16) short Bsm[2][4096];
  f32x4 acc[4][4];
  #pragma unroll
  for (int i = 0; i < 4; ++i)
    #pragma unroll
    for (int j = 0; j < 4; ++j) acc[i][j] = (f32x4){0.f, 0.f, 0.f, 0.f};

  const int bx = blockIdx.x, by = blockIdx.y;
  const short* Bt; int mode, nl0;
  if (bx < 16)      { Bt = Wqt;  nl0 = bx * 128;        mode = 0; }
  else if (bx < 20) { Bt = Wkt;  nl0 = (bx - 16) * 128; mode = 1; }
  else if (bx < 24) { Bt = Wvt;  nl0 = (bx - 20) * 128; mode = 2; }
  else              { Bt = WABt; nl0 = 0;               mode = 3; }

  gemm128_core(xb, Bt, by * 128, nl0, 2048, Asm, Bsm, acc);

  const int tid = threadIdx.x, lane = tid & 63, w = tid >> 6;
  const int lr = lane & 15, g4 = lane >> 4, wm = w >> 1, wn = w & 1;
  #pragma unroll
  for (int mi = 0; mi < 4; ++mi) {
    #pragma unroll
    for (int ni = 0; ni < 4; ++ni) {
      int mb = by * 128 + wm * 64 + mi * 16 + g4 * 4;
      int nc = nl0 + wn * 64 + ni * 16 + lr;
      if (mode == 0) {
        #pragma unroll
        for (int r = 0; r < 4; ++r)
          Qb[(size_t)(mb + r) * 2048 + nc] = f2bf(acc[mi][ni][r]);
      } else if (mode == 1) {
        #pragma unroll
        for (int r = 0; r < 4; ++r)
          Kb[(size_t)(mb + r) * 512 + nc] = f2bf(acc[mi][ni][r]);
      } else if (mode == 2) {
        uint2 uu;
        uu.x = packbf(acc[mi][ni][0], acc[mi][ni][1]);
        uu.y = packbf(acc[mi][ni][2], acc[mi][ni][3]);
        *(uint2*)(Vtb + (size_t)nc * 2048 + mb) = uu;   // V^T [512][2048]
      } else {
        if (wn == 0) {
          int col = ni * 16 + lr;   // 0..63
          #pragma unroll
          for (int r = 0; r < 4; ++r) {
            float sv = acc[mi][ni][r];
            if (col < 32) {
              Ab[(size_t)(mb + r) * 32 + col] = f2bf(sv * LOG2E);
            } else {
              Bb[(size_t)(mb + r) * 32 + (col - 32)] = f2bf(sv);
            }
          }
        }
      }
    }
  }
}

// Output projection: out = AO(bf16) @ Wo -> fp32. grid (16,16).
__global__ __launch_bounds__(256, 3) void gemm_out_kernel(
    const short* __restrict__ AO, const short* __restrict__ Wot,
    float* __restrict__ out)
{
  __shared__ __align__(16) short Asm[2][4096];
  __shared__ __align__(16) short Bsm[2][4096];
  f32x4 acc[4][4];
  #pragma unroll
  for (int i = 0; i < 4; ++i)
    #pragma unroll
    for (int j = 0; j < 4; ++j) acc[i][j] = (f32x4){0.f, 0.f, 0.f, 0.f};

  gemm128_core(AO, Wot, blockIdx.y * 128, blockIdx.x * 128, 2048, Asm, Bsm, acc);

  const int tid = threadIdx.x, lane = tid & 63, w = tid >> 6;
  const int lr = lane & 15, g4 = lane >> 4, wm = w >> 1, wn = w & 1;
  #pragma unroll
  for (int mi = 0; mi < 4; ++mi)
    #pragma unroll
    for (int ni = 0; ni < 4; ++ni) {
      int mb = blockIdx.y * 128 + wm * 64 + mi * 16 + g4 * 4;
      int nc = blockIdx.x * 128 + wn * 64 + ni * 16 + lr;
      #pragma unroll
      for (int r = 0; r < 4; ++r)
        out[(size_t)(mb + r) * 2048 + nc] = acc[mi][ni][r];
    }
}

// ---------------------------------------------------------------------------
// Flash attention, bf16 MFMA, exp2-domain softmax, 48KB LDS -> 3 blocks/CU.
// LDS: Kb0 @0 (16K), Kb1 @16384 (16K), Vs @32768 (16K).
// B tile lives in 16 VGPRs (loaded per tile). P overlays dead Kcur[0:8K].
// Counted vmcnt: per-tile issue order K(4) -> B(4) -> V(4).
// grid (16 heads, 32 y), qt = (y<16) ? 31-y : y-16 (balanced pairing).
// ---------------------------------------------------------------------------
__global__ __launch_bounds__(256, 3) void attn_kernel(
    const short* __restrict__ Qg, const short* __restrict__ Kg,
    const short* __restrict__ Vtg, const short* __restrict__ Ag,
    const short* __restrict__ Bg, const float* __restrict__ pol_dir,
    const float* __restrict__ pol_gate, const float* __restrict__ gtp_gamma,
    short* __restrict__ AO)
{
  __shared__ __align__(16) char lds[49152];
  char* const Vs = lds + 32768;

  const int tid = threadIdx.x;
  const int lane = tid & 63, w = tid >> 6;
  const int lr = lane & 15, g4 = lane >> 4;
  const int h  = blockIdx.x;
  const int by = blockIdx.y;
  const int qt = (by < 16) ? (31 - by) : (by - 16);   // balanced pairing
  const int q0 = qt * 64;
  const int kvh = h >> 2;
  const short* Kh = Kg + kvh * 128;
  const short* Vh = Vtg + (size_t)(kvh * 128) * 2048;

  float pol   = fminf(fmaxf(pol_dir[h], -1.f), 1.f);
  float gamma = fmaxf(log1pf(__expf(gtp_gamma[h])), 1e-6f);
  float gate  = (1.f / (1.f + __expf(-pol_gate[h]))) * LOG2E;
  const float c_h  = -(pol * (1.f / 4096.f) + gamma) * LOG2E;  // log2-domain
  const float c16  = 16.f * c_h;
  const float chr1 = c_h, chr2 = c_h + c_h, chr3 = chr2 + c_h;
  const float sc = 0.08838834764831845f * LOG2E;   // log2e/sqrt(128)
  const f32x4 z4 = {0.f, 0.f, 0.f, 0.f};

  // ---- prologue: Q -> Kb1 overlay, A -> Vs overlay (ds_write) ----
  #pragma unroll
  for (int s = 0; s < 4; ++s) {
    int c = tid + s * 256;
    int row = c >> 4, sl = c & 15;
    int4 v = *(const int4*)(Qg + (size_t)(q0 + row) * 2048 + h * 128 + sl * 8);
    *(int4*)(lds + 16384 + row * 256 + ((sl * 16) ^ ((row & 7) << 4))) = v;
  }
  {
    int row = tid >> 2, sl = tid & 3;
    int4 va = *(const int4*)(Ag + (size_t)(q0 + row) * 32 + sl * 8);
    *(int4*)(Vs + row * 80 + sl * 16) = va;
  }
  asm volatile("s_waitcnt lgkmcnt(0)" ::: "memory");
  __builtin_amdgcn_s_barrier();

  // hoist Q frags (q-row = w*16+lr) and A frag
  bf16x8 qf[4];
  #pragma unroll
  for (int kk = 0; kk < 4; ++kk)
    qf[kk] = *(const bf16x8*)(lds + 16384 + (w * 16 + lr) * 256 +
                              ((kk * 64 + g4 * 16) ^ ((lr & 7) << 4)));
  bf16x8 afr = *(const bf16x8*)(Vs + (w * 16 + lr) * 80 + g4 * 16);
  asm volatile("s_waitcnt lgkmcnt(0)" ::: "memory");
  __builtin_amdgcn_s_barrier();   // overlays now dead

  // ---- issue K0 -> buf0 (4), B0 -> regs (4), V0 -> Vs (4) ----
  #pragma unroll
  for (int s = 0; s < 4; ++s) {
    int idx = (w * 4 + s) * 64 + lane;
    int row = idx >> 4, slot = idx & 15;
    gload_lds16(Kh + (size_t)row * 512 + (slot ^ (row & 7)) * 8,
                lds + (w * 4 + s) * 1024);
  }
  bf16x8 bcur[4];
  #pragma unroll
  for (int cb = 0; cb < 4; ++cb)
    bcur[cb] = *(const bf16x8*)(Bg + (size_t)(cb * 16 + lr) * 32 + g4 * 8);
  #pragma unroll
  for (int s = 0; s < 4; ++s) {
    int idx = (w * 4 + s) * 64 + lane;
    int row = idx >> 3, slot = idx & 7;
    gload_lds16(Vh + (size_t)row * 2048 + (slot ^ (row & 7)) * 8,
                Vs + (w * 4 + s) * 1024);
  }

  f32x4 acc_o[8];
  #pragma unroll
  for (int i = 0; i < 8; ++i) acc_o[i] = z4;
  float m_st = -INFINITY, l_st = 0.f;

  for (int jt = 0; jt <= qt; ++jt) {
    const int j0 = jt * 64;
    const bool pf = (jt < qt);
    char* Kcur = lds + ((jt & 1) << 14);
    char* Knxt = lds + (((jt + 1) & 1) << 14);

    // ---- issue K[jt+1] -> Knxt ----
    if (pf) {
      #pragma unroll
      for (int s = 0; s < 4; ++s) {
        int idx = (w * 4 + s) * 64 + lane;
        int row = idx >> 4, slot = idx & 15;
        gload_lds16(Kh + (size_t)(j0 + 64 + row) * 512 + (slot ^ (row & 7)) * 8,
                    Knxt + (w * 4 + s) * 1024);
      }
    }
    // (1) K[jt] + B[jt] landed (V[jt] + K[jt+1] may remain in flight)
    if (pf) asm volatile("s_waitcnt vmcnt(8)" ::: "memory");
    else    asm volatile("s_waitcnt vmcnt(4)" ::: "memory");
    __builtin_amdgcn_s_barrier();

    // ---- S^T = K.Q^T, md = Bm.A^T (B from regs) ----
    f32x4 acc_s[4], md4[4];
    __builtin_amdgcn_s_setprio(1);
    #pragma unroll
    for (int cb = 0; cb < 4; ++cb) {
      acc_s[cb] = z4;
      #pragma unroll
      for (int kk = 0; kk < 4; ++kk) {
        bf16x8 kf = *(const bf16x8*)(Kcur + (cb * 16 + lr) * 256 +
                                     ((kk * 64 + g4 * 16) ^ ((lr & 7) << 4)));
        acc_s[cb] = MFMA16(kf, qf[kk], acc_s[cb], 0, 0, 0);
      }
      md4[cb] = MFMA16(bcur[cb], afr, z4, 0, 0, 0);
    }
    __builtin_amdgcn_s_setprio(0);

    // ---- issue B[jt+1] -> bcur (WAR after bias MFMA consumed) ----
    if (pf) {
      #pragma unroll
      for (int cb = 0; cb < 4; ++cb)
        bcur[cb] = *(const bf16x8*)(Bg + (size_t)(j0 + 64 + cb * 16 + lr) * 32 +
                                    g4 * 8);
    }

    // ---- bias + (diag-only) mask, log2 domain ----
    const int dq = q0 + w * 16 + lr - j0;    // qi - j0
    float bq = c_h * (float)(dq - g4 * 4);
    #pragma unroll
    for (int cb = 0; cb < 4; ++cb) {
      float bcb = bq - c16 * (float)cb;
      float sig0 = rcpf(1.f + ex2(-md4[cb][0]));
      float sig1 = rcpf(1.f + ex2(-md4[cb][1]));
      float sig2 = rcpf(1.f + ex2(-md4[cb][2]));
      float sig3 = rcpf(1.f + ex2(-md4[cb][3]));
      acc_s[cb][0] = fmaf(acc_s[cb][0], sc, fmaf(gate, sig0, bcb));
      acc_s[cb][1] = fmaf(acc_s[cb][1], sc, fmaf(gate, sig1, bcb - chr1));
      acc_s[cb][2] = fmaf(acc_s[cb][2], sc, fmaf(gate, sig2, bcb - chr2));
      acc_s[cb][3] = fmaf(acc_s[cb][3], sc, fmaf(gate, sig3, bcb - chr3));
    }
    if (jt == qt) {
      #pragma unroll
      for (int cb = 0; cb < 4; ++cb)
        #pragma unroll
        for (int r = 0; r < 4; ++r)
          if (cb * 16 + g4 * 4 + r > dq) acc_s[cb][r] = -INFINITY;
    }

    // ---- online softmax, defer-max (THR = 8*log2e) ----
    float t0 = fmaxf(fmaxf(acc_s[0][0], acc_s[0][1]), acc_s[0][2]);
    float t1 = fmaxf(fmaxf(acc_s[0][3], acc_s[1][0]), acc_s[1][1]);
    float t2 = fmaxf(fmaxf(acc_s[1][2], acc_s[1][3]), acc_s[2][0]);
    float t3 = fmaxf(fmaxf(acc_s[2][1], acc_s[2][2]), acc_s[2][3]);
    float t4 = fmaxf(fmaxf(acc_s[3][0], acc_s[3][1]), acc_s[3][2]);
    float mx = fmaxf(fmaxf(fmaxf(t0, t1), t2),
                     fmaxf(fmaxf(t3, t4), acc_s[3][3]));
    mx = fmaxf(mx, __shfl_xor(mx, 16));
    mx = fmaxf(mx, __shfl_xor(mx, 32));
    if (!__all(mx - m_st <= 11.5415603f)) {
      float mn = fmaxf(m_st, mx);
      float es = ex2(m_st - mn);   // first tile: exp2(-inf)=0
      l_st *= es;
      m_st = mn;
      float es4[4];
      #pragma unroll
      for (int r = 0; r < 4; ++r) es4[r] = __shfl(es, g4 * 4 + r, 64);
      #pragma unroll
      for (int db = 0; db < 8; ++db)
        #pragma unroll
        for (int r = 0; r < 4; ++r) acc_o[db][r] *= es4[r];
    }
    float rs = 0.f;
    #pragma unroll
    for (int cb = 0; cb < 4; ++cb)
      #pragma unroll
      for (int r = 0; r < 4; ++r) {
        float p = ex2(acc_s[cb][r] - m_st);
        acc_s[cb][r] = p;
        rs += p;
      }
    rs += __shfl_xor(rs, 16);
    rs += __shfl_xor(rs, 32);
    l_st += rs;

    // (2) V[jt] visible to all waves; Kcur reads done -> P region writable
    if (pf) asm volatile("s_waitcnt vmcnt(8)" ::: "memory");
    else    asm volatile("s_waitcnt vmcnt(0)" ::: "memory");
    __builtin_amdgcn_s_barrier();

    // ---- P -> Kcur[0:8K] (per-wave region), then PV ----
    char* Pw = Kcur + w * 2048;
    #pragma unroll
    for (int cb = 0; cb < 4; ++cb) {
      uint2 uu;
      uu.x = cvtpk(acc_s[cb][0], acc_s[cb][1]);
      uu.y = cvtpk(acc_s[cb][2], acc_s[cb][3]);
      *(uint2*)(Pw + lr * 128 + ((cb * 32 + g4 * 8) ^ ((lr & 7) << 4))) = uu;
    }
    asm volatile("s_waitcnt lgkmcnt(0)" ::: "memory");
    __builtin_amdgcn_sched_barrier(0);
    __builtin_amdgcn_s_setprio(1);
    #pragma unroll
    for (int kk = 0; kk < 2; ++kk) {
      bf16x8 pfr = *(const bf16x8*)(Pw + lr * 128 +
                                    ((kk * 64 + g4 * 16) ^ ((lr & 7) << 4)));
      #pragma unroll
      for (int db = 0; db < 8; ++db) {
        bf16x8 vf = *(const bf16x8*)(Vs + (db * 16 + lr) * 128 +
                                     ((kk * 64 + g4 * 16) ^ ((lr & 7) << 4)));
        acc_o[db] = MFMA16(pfr, vf, acc_o[db], 0, 0, 0);
      }
    }
    __builtin_amdgcn_s_setprio(0);
    __builtin_amdgcn_sched_barrier(0);

    // (3) all waves' P/V reads done -> safe to restage V (and K[jt+2] next top)
    __builtin_amdgcn_s_barrier();
    if (pf) {
      #pragma unroll
      for (int s = 0; s < 4; ++s) {
        int idx = (w * 4 + s) * 64 + lane;
        int row = idx >> 3, slot = idx & 7;
        gload_lds16(Vh + (size_t)row * 2048 + (j0 + 64) + (slot ^ (row & 7)) * 8,
                    Vs + (w * 4 + s) * 1024);
      }
    }
  }

  // epilogue: normalize, store bf16 AO. acc rows q = g4*4+r, col d = db*16+lr.
  float lrcp[4];
  #pragma unroll
  for (int r = 0; r < 4; ++r) lrcp[r] = 1.f / __shfl(l_st, g4 * 4 + r, 64);
  #pragma unroll
  for (int db = 0; db < 8; ++db)
    #pragma unroll
    for (int r = 0; r < 4; ++r)
      AO[(size_t)(q0 + w * 16 + g4 * 4 + r) * 2048 + h * 128 + db * 16 + lr] =
          f2bf(acc_o[db][r] * lrcp[r]);
}

// ---------------------------------------------------------------------------
// Launch
// ---------------------------------------------------------------------------
extern "C" void kernel_launch(void* const* d_in, const int* in_sizes, int n_in,
                              void* d_out, int out_size, void* d_ws, size_t ws_size,
                              hipStream_t stream) {
  const float* x         = (const float*)d_in[0];
  const float* Wq        = (const float*)d_in[1];
  const float* Wk        = (const float*)d_in[2];
  const float* Wv        = (const float*)d_in[3];
  const float* Wo        = (const float*)d_in[4];
  const float* pol_dir   = (const float*)d_in[5];
  const float* pol_WA    = (const float*)d_in[6];
  const float* pol_WB    = (const float*)d_in[7];
  const float* pol_gate  = (const float*)d_in[8];
  const float* gtp_gamma = (const float*)d_in[9];
  float* out = (float*)d_out;

  char* ws = (char*)d_ws;
  short* Qb   = (short*)(ws);                    // 2048x2048 bf16 = 8 MB
  short* Kb   = (short*)(ws + 8388608);          // 2048x512  bf16 = 2 MB
  short* Vtb  = (short*)(ws + 10485760);         // 512x2048  bf16 = 2 MB (V^T)
  short* Ab   = (short*)(ws + 12582912);         // 2048x32   bf16 = 128 KB
  short* Bb   = (short*)(ws + 12713984);         // 2048x32   bf16 = 128 KB
  short* xb   = (short*)(ws + 12845056);         // 8 MB (reused as Wot after qkv)
  short* Wot  = xb;                              // written by mid_kernel (xb dead)
  short* Wqt  = (short*)(ws + 21233664);         // 8 MB (reused as AO after qkv)
  short* AO   = Wqt;                             // written by attn (Wqt dead)
  short* Wkt  = (short*)(ws + 29622272);         // 2 MB
  short* Wvt  = (short*)(ws + 31719424);         // 2 MB
  short* WABt = (short*)(ws + 33816576);         // 128x2048 bf16 = 512 KB
  // total 34.3 MB

  prep_kernel<<<10368, 256, 0, stream>>>(x, Wq, Wk, Wv, pol_WA, pol_WB,
                                         xb, Wqt, Wkt, Wvt, WABt);
  gemm_qkv_kernel<<<dim3(25, 16), 256, 0, stream>>>(xb, Wqt, Wkt, Wvt, WABt,
                                                    Qb, Kb, Vtb, Ab, Bb);
  mid_kernel<<<14336, 256, 0, stream>>>(Wo, Wot, Qb, Kb);
  attn_kernel<<<dim3(16, 32), 256, 0, stream>>>(Qb, Kb, Vtb, Ab, Bb,
                                                pol_dir, pol_gate, gtp_gamma, AO);
  gemm_out_kernel<<<dim3(16, 16), 256, 0, stream>>>(AO, Wot, out);
}

// Round 9
// 169.030 us; speedup vs baseline: 1.0931x; 1.0931x over previous
//
#include <hip/hip_runtime.h>
#include <math.h>

// ---------------------------------------------------------------------------
// Types / helpers
// ---------------------------------------------------------------------------
typedef short bf16x8 __attribute__((ext_vector_type(8)));   // 8 bf16 (4 VGPRs)
typedef float f32x4  __attribute__((ext_vector_type(4)));

#define MFMA16 __builtin_amdgcn_mfma_f32_16x16x32_bf16
#define LOG2E 1.4426950408889634f

static __device__ __forceinline__ short f2bf(float f) {
  union { float f; unsigned u; } x; x.f = f;
  unsigned r = (x.u + 0x7FFFu + ((x.u >> 16) & 1u)) >> 16;  // RTNE
  return (short)r;
}
static __device__ __forceinline__ unsigned packbf(float a, float b) {
  return (unsigned)(unsigned short)f2bf(a) | ((unsigned)(unsigned short)f2bf(b) << 16);
}
static __device__ __forceinline__ float bf2f(short s) {
  union { unsigned u; float f; } x; x.u = ((unsigned)(unsigned short)s) << 16;
  return x.f;
}
static __device__ __forceinline__ void gload_lds16(const void* g, void* l) {
  __builtin_amdgcn_global_load_lds((const __attribute__((address_space(1))) void*)g,
                                   (__attribute__((address_space(3))) void*)l, 16, 0, 0);
}
static __device__ __forceinline__ float ex2(float x) {
  float r; asm("v_exp_f32 %0, %1" : "=v"(r) : "v"(x)); return r;
}
static __device__ __forceinline__ float rcpf(float x) {
  float r; asm("v_rcp_f32 %0, %1" : "=v"(r) : "v"(x)); return r;
}
static __device__ __forceinline__ unsigned cvtpk(float lo, float hi) {
  unsigned r; asm("v_cvt_pk_bf16_f32 %0, %1, %2" : "=v"(r) : "v"(lo), "v"(hi));
  return r;
}

// ---------------------------------------------------------------------------
// Transpose one 32x32 tile: fp32 in [K][N] -> bf16 out [N][K]
// ---------------------------------------------------------------------------
__device__ __forceinline__ void tr_tile(
    const float* __restrict__ in, short* __restrict__ out,
    int K, int N, int nt, int kt, float (*t)[33])
{
  int n0 = nt * 32, k0 = kt * 32;
  int tx = threadIdx.x & 31, ty = threadIdx.x >> 5;
  #pragma unroll
  for (int i = 0; i < 4; ++i)
    t[ty + 8 * i][tx] = in[(size_t)(k0 + ty + 8 * i) * N + n0 + tx];
  __syncthreads();
  #pragma unroll
  for (int i = 0; i < 4; ++i)
    out[(size_t)(n0 + ty + 8 * i) * K + k0 + tx] = f2bf(t[tx][ty + 8 * i]);
}

// Fused prep: Wq/Wk/Wv/WA/WB transposes + x fp32->bf16 convert. grid 10368.
__global__ __launch_bounds__(256) void prep_kernel(
    const float* __restrict__ x, const float* __restrict__ Wq,
    const float* __restrict__ Wk, const float* __restrict__ Wv,
    const float* __restrict__ WA, const float* __restrict__ WB,
    short* __restrict__ xb, short* __restrict__ Wqt, short* __restrict__ Wkt,
    short* __restrict__ Wvt, short* __restrict__ WABt)
{
  __shared__ float t[32][33];
  int b = blockIdx.x;
  if (b < 4096)       tr_tile(Wq, Wqt, 2048, 2048, b & 63, b >> 6, t);
  else if (b < 5120)  { int c = b - 4096; tr_tile(Wk, Wkt, 2048, 512, c & 15, c >> 4, t); }
  else if (b < 6144)  { int c = b - 5120; tr_tile(Wv, Wvt, 2048, 512, c & 15, c >> 4, t); }
  else if (b < 6208)  { int c = b - 6144; tr_tile(WA, WABt, 2048, 32, 0, c, t); }
  else if (b < 6272)  { int c = b - 6208; tr_tile(WB, WABt + 32 * 2048, 2048, 32, 0, c, t); }
  else {
    int i = (b - 6272) * 256 + threadIdx.x;          // 4096 blocks, 1M float4
    float4 v = ((const float4*)x)[i];
    short4 o; o.x = f2bf(v.x); o.y = f2bf(v.y); o.z = f2bf(v.z); o.w = f2bf(v.w);
    ((short4*)xb)[i] = o;
  }
}

// Fused mid: Wo transpose + RoPE on Q/K. grid 4096 + 10240 = 14336.
__global__ __launch_bounds__(256) void mid_kernel(
    const float* __restrict__ Wo, short* __restrict__ Wot,
    short* __restrict__ Q, short* __restrict__ K)
{
  __shared__ float t[32][33];
  int b = blockIdx.x;
  if (b < 4096) { tr_tile(Wo, Wot, 2048, 2048, b & 63, b >> 6, t); return; }
  int idx = (b - 4096) * 256 + threadIdx.x;   // < 2048*20*64
  int d  = idx & 63;
  int hh = (idx >> 6) % 20;
  int tt = idx / (20 * 64);
  short* base = (hh < 16) ? Q + (size_t)tt * 2048 + hh * 128 + d
                          : K + (size_t)tt * 512 + (hh - 16) * 128 + d;
  float inv = __expf((float)d * -0.14391156831212789f);  // 10000^(-d/64)
  float ang = (float)tt * inv;
  float sn, cs;
  __sincosf(ang, &sn, &cs);
  float x1 = bf2f(base[0]), x2 = bf2f(base[64]);
  base[0]  = f2bf(x1 * cs - x2 * sn);
  base[64] = f2bf(x2 * cs + x1 * sn);
}

// ---------------------------------------------------------------------------
// bf16 MFMA GEMM core, C 128(M)x64(N) tile, BK=32, SINGLE-buffer LDS with
// full __syncthreads drains (deterministic; round-6 structure, 64-wide).
// A [M][K], Bt [N][K] bf16. 256 threads, 4 waves 2(M)x2(N); 4x2 frags/wave.
// ---------------------------------------------------------------------------
__device__ __forceinline__ void gemm12864_core(
    const short* __restrict__ A, const short* __restrict__ Bt,
    int m0, int n0, int Kd, short* Asm, short* Bsm, f32x4 acc[4][2])
{
  const int tid = threadIdx.x;
  const int lane = tid & 63, w = tid >> 6;
  const int lr = lane & 15, g4 = lane >> 4;
  const int wm = w >> 1, wn = w & 1;

  for (int k0 = 0; k0 < Kd; k0 += 32) {
    #pragma unroll
    for (int s = 0; s < 2; ++s) {
      int c = (s * 4 + w) * 64 + lane;   // A chunks 0..511
      int row = c >> 2, q = c & 3;       // row 0..127, 16B chunk q
      gload_lds16(A + (size_t)(m0 + row) * Kd + k0 + q * 8, Asm + c * 8);
    }
    {
      int c = tid;                        // B chunks 0..255 (row 0..63)
      int row = c >> 2, q = c & 3;
      gload_lds16(Bt + (size_t)(n0 + row) * Kd + k0 + q * 8, Bsm + c * 8);
    }
    __syncthreads();                      // drains vmcnt+lgkmcnt (compiler)
    bf16x8 af[4], bff[2];
    #pragma unroll
    for (int mi = 0; mi < 4; ++mi)
      af[mi] = *(const bf16x8*)(Asm + (wm * 64 + mi * 16 + lr) * 32 + g4 * 8);
    #pragma unroll
    for (int ni = 0; ni < 2; ++ni)
      bff[ni] = *(const bf16x8*)(Bsm + (wn * 32 + ni * 16 + lr) * 32 + g4 * 8);
    #pragma unroll
    for (int mi = 0; mi < 4; ++mi)
      #pragma unroll
      for (int ni = 0; ni < 2; ++ni)
        acc[mi][ni] = MFMA16(af[mi], bff[ni], acc[mi][ni], 0, 0, 0);
    __syncthreads();                      // WAR: reads done before restage
  }
}

// Fused QKV + low-rank AB projection. grid (49, 16).
// bx<32: Q, bx<40: K, bx<48: V (transposed out), bx==48: A|B (one 64-col tile).
// A-projection pre-scaled by log2(e) for exp2-domain attn.
__global__ __launch_bounds__(256, 3) void gemm_qkv_kernel(
    const short* __restrict__ xb, const short* __restrict__ Wqt,
    const short* __restrict__ Wkt, const short* __restrict__ Wvt,
    const short* __restrict__ WABt,
    short* __restrict__ Qb, short* __restrict__ Kb, short* __restrict__ Vtb,
    short* __restrict__ Ab, short* __restrict__ Bb)
{
  __shared__ __align__(16) short Asm[128 * 32];
  __shared__ __align__(16) short Bsm[64 * 32];
  f32x4 acc[4][2];
  #pragma unroll
  for (int i = 0; i < 4; ++i)
    #pragma unroll
    for (int j = 0; j < 2; ++j) acc[i][j] = (f32x4){0.f, 0.f, 0.f, 0.f};

  const int bx = blockIdx.x, by = blockIdx.y;
  const short* Bt; int mode, nl0;
  if (bx < 32)      { Bt = Wqt;  nl0 = bx * 64;        mode = 0; }
  else if (bx < 40) { Bt = Wkt;  nl0 = (bx - 32) * 64; mode = 1; }
  else if (bx < 48) { Bt = Wvt;  nl0 = (bx - 40) * 64; mode = 2; }
  else              { Bt = WABt; nl0 = 0;              mode = 3; }

  gemm12864_core(xb, Bt, by * 128, nl0, 2048, Asm, Bsm, acc);

  const int tid = threadIdx.x, lane = tid & 63, w = tid >> 6;
  const int lr = lane & 15, g4 = lane >> 4, wm = w >> 1, wn = w & 1;
  #pragma unroll
  for (int mi = 0; mi < 4; ++mi) {
    #pragma unroll
    for (int ni = 0; ni < 2; ++ni) {
      int mb = by * 128 + wm * 64 + mi * 16 + g4 * 4;
      int ncl = wn * 32 + ni * 16 + lr;    // 0..63 within tile
      int nc = nl0 + ncl;
      if (mode == 0) {
        #pragma unroll
        for (int r = 0; r < 4; ++r)
          Qb[(size_t)(mb + r) * 2048 + nc] = f2bf(acc[mi][ni][r]);
      } else if (mode == 1) {
        #pragma unroll
        for (int r = 0; r < 4; ++r)
          Kb[(size_t)(mb + r) * 512 + nc] = f2bf(acc[mi][ni][r]);
      } else if (mode == 2) {
        uint2 uu;
        uu.x = packbf(acc[mi][ni][0], acc[mi][ni][1]);
        uu.y = packbf(acc[mi][ni][2], acc[mi][ni][3]);
        *(uint2*)(Vtb + (size_t)nc * 2048 + mb) = uu;   // V^T [512][2048]
      } else {
        #pragma unroll
        for (int r = 0; r < 4; ++r) {
          float sv = acc[mi][ni][r];
          if (ncl < 32) Ab[(size_t)(mb + r) * 32 + ncl] = f2bf(sv * LOG2E);
          else          Bb[(size_t)(mb + r) * 32 + (ncl - 32)] = f2bf(sv);
        }
      }
    }
  }
}

// Output projection: out = AO(bf16) @ Wo -> fp32. grid (32, 16).
__global__ __launch_bounds__(256, 3) void gemm_out_kernel(
    const short* __restrict__ AO, const short* __restrict__ Wot,
    float* __restrict__ out)
{
  __shared__ __align__(16) short Asm[128 * 32];
  __shared__ __align__(16) short Bsm[64 * 32];
  f32x4 acc[4][2];
  #pragma unroll
  for (int i = 0; i < 4; ++i)
    #pragma unroll
    for (int j = 0; j < 2; ++j) acc[i][j] = (f32x4){0.f, 0.f, 0.f, 0.f};

  gemm12864_core(AO, Wot, blockIdx.y * 128, blockIdx.x * 64, 2048, Asm, Bsm, acc);

  const int tid = threadIdx.x, lane = tid & 63, w = tid >> 6;
  const int lr = lane & 15, g4 = lane >> 4, wm = w >> 1, wn = w & 1;
  #pragma unroll
  for (int mi = 0; mi < 4; ++mi)
    #pragma unroll
    for (int ni = 0; ni < 2; ++ni) {
      int mb = blockIdx.y * 128 + wm * 64 + mi * 16 + g4 * 4;
      int nc = blockIdx.x * 64 + wn * 32 + ni * 16 + lr;
      #pragma unroll
      for (int r = 0; r < 4; ++r)
        out[(size_t)(mb + r) * 2048 + nc] = acc[mi][ni][r];
    }
}

// ---------------------------------------------------------------------------
// Flash attention (round-6 version, verbatim — measured good: 75us, no spill).
// bf16 MFMA, exp2-domain softmax. grid (16 heads, 32 y),
// qt = (y<16) ? 31-y : y-16 (balanced pairing). LDS-double-buffered K
// (global_load_lds, pre-swizzled source), single V staged after the end
// barrier (counted vmcnt before PV). LDS 66KB -> 2 blocks/CU.
// ---------------------------------------------------------------------------
__global__ __launch_bounds__(256, 2) void attn_kernel(
    const short* __restrict__ Qg, const short* __restrict__ Kg,
    const short* __restrict__ Vtg, const short* __restrict__ Ag,
    const short* __restrict__ Bg, const float* __restrict__ pol_dir,
    const float* __restrict__ pol_gate, const float* __restrict__ gtp_gamma,
    short* __restrict__ AO)
{
  // layout: Kb0 @0 (16K), Kb1 @16384 (16K, Q overlay), Vs @32768 (16K),
  //         Ps @49152 (8K, A overlay), Bs0 @57344 (5K), Bs1 @62464 (5K)
  __shared__ __align__(16) char lds[67584];
  char* const Vs = lds + 32768;
  char* const Ps = lds + 49152;

  const int tid = threadIdx.x;
  const int lane = tid & 63, w = tid >> 6;
  const int lr = lane & 15, g4 = lane >> 4;
  const int h  = blockIdx.x;
  const int by = blockIdx.y;
  const int qt = (by < 16) ? (31 - by) : (by - 16);   // balanced pairing
  const int q0 = qt * 64;
  const int kvh = h >> 2;
  const short* Kh = Kg + kvh * 128;
  const short* Vh = Vtg + (size_t)(kvh * 128) * 2048;

  float pol   = fminf(fmaxf(pol_dir[h], -1.f), 1.f);
  float gamma = fmaxf(log1pf(__expf(gtp_gamma[h])), 1e-6f);
  float gate  = (1.f / (1.f + __expf(-pol_gate[h]))) * LOG2E;
  const float c_h  = -(pol * (1.f / 4096.f) + gamma) * LOG2E;  // log2-domain
  const float c16  = 16.f * c_h;
  const float chr1 = c_h, chr2 = c_h + c_h, chr3 = chr2 + c_h;
  const float sc = 0.08838834764831845f * LOG2E;   // log2e/sqrt(128)
  const f32x4 z4 = {0.f, 0.f, 0.f, 0.f};

  // ---- prologue: K0/V0 via global_load_lds (pre-swizzled source) ----
  #pragma unroll
  for (int s = 0; s < 4; ++s) {
    int idx = (w * 4 + s) * 64 + lane;
    int row = idx >> 4, slot = idx & 15;
    gload_lds16(Kh + (size_t)row * 512 + (slot ^ (row & 7)) * 8,
                lds + (w * 4 + s) * 1024);
  }
  #pragma unroll
  for (int s = 0; s < 4; ++s) {
    int idx = (w * 4 + s) * 64 + lane;
    int row = idx >> 3, slot = idx & 7;
    gload_lds16(Vh + (size_t)row * 2048 + (slot ^ (row & 7)) * 8,
                Vs + (w * 4 + s) * 1024);
  }
  // Q -> Kb1 overlay (swizzled), A -> Ps overlay, B0 -> Bs0 (reg path)
  #pragma unroll
  for (int s = 0; s < 4; ++s) {
    int c = tid + s * 256;
    int row = c >> 4, sl = c & 15;
    int4 v = *(const int4*)(Qg + (size_t)(q0 + row) * 2048 + h * 128 + sl * 8);
    *(int4*)(lds + 16384 + row * 256 + ((sl * 16) ^ ((row & 7) << 4))) = v;
  }
  {
    int row = tid >> 2, sl = tid & 3;
    int4 va = *(const int4*)(Ag + (size_t)(q0 + row) * 32 + sl * 8);
    *(int4*)(Ps + row * 80 + sl * 16) = va;
    int4 vb = *(const int4*)(Bg + (size_t)row * 32 + sl * 8);
    *(int4*)(lds + 57344 + row * 80 + sl * 16) = vb;
  }
  asm volatile("s_waitcnt vmcnt(0) lgkmcnt(0)" ::: "memory");
  __builtin_amdgcn_s_barrier();

  // hoist Q frags (q-row = w*16+lr) and A frag
  bf16x8 qf[4];
  #pragma unroll
  for (int kk = 0; kk < 4; ++kk)
    qf[kk] = *(const bf16x8*)(lds + 16384 + (w * 16 + lr) * 256 +
                              ((kk * 64 + g4 * 16) ^ ((lr & 7) << 4)));
  bf16x8 afr = *(const bf16x8*)(Ps + (w * 16 + lr) * 80 + g4 * 16);
  asm volatile("s_waitcnt lgkmcnt(0)" ::: "memory");
  __builtin_amdgcn_s_barrier();   // Kb1 + Ps now free for K-dbuf / P

  f32x4 acc_o[8];
  #pragma unroll
  for (int i = 0; i < 8; ++i) acc_o[i] = z4;
  float m_st = -INFINITY, l_st = 0.f;
  char* Pw = Ps + w * 2048;

  for (int jt = 0; jt <= qt; ++jt) {
    const int j0 = jt * 64;
    const bool pf = (jt < qt);
    char* Kcur = lds + ((jt & 1) << 14);
    char* Knxt = lds + (((jt + 1) & 1) << 14);
    char* Bcur = lds + 57344 + (jt & 1) * 5120;
    char* Bnxt = lds + 57344 + ((jt + 1) & 1) * 5120;

    // ---- issue next K tile (LDS dbuf, no VGPR cost) + B reg load ----
    int4 breg;
    if (pf) {
      int brow = tid >> 2, bsl = tid & 3;
      breg = *(const int4*)(Bg + (size_t)(j0 + 64 + brow) * 32 + bsl * 8);
      #pragma unroll
      for (int s = 0; s < 4; ++s) {
        int idx = (w * 4 + s) * 64 + lane;
        int row = idx >> 4, slot = idx & 15;
        gload_lds16(Kh + (size_t)(j0 + 64 + row) * 512 + (slot ^ (row & 7)) * 8,
                    Knxt + (w * 4 + s) * 1024);
      }
    }

    // ---- S^T = K.Q^T, md = Bm.A^T ----
    f32x4 acc_s[4], md4[4];
    __builtin_amdgcn_s_setprio(1);
    #pragma unroll
    for (int cb = 0; cb < 4; ++cb) {
      acc_s[cb] = z4;
      #pragma unroll
      for (int kk = 0; kk < 4; ++kk) {
        bf16x8 kf = *(const bf16x8*)(Kcur + (cb * 16 + lr) * 256 +
                                     ((kk * 64 + g4 * 16) ^ ((lr & 7) << 4)));
        acc_s[cb] = MFMA16(kf, qf[kk], acc_s[cb], 0, 0, 0);
      }
      bf16x8 bmf = *(const bf16x8*)(Bcur + (cb * 16 + lr) * 80 + g4 * 16);
      md4[cb] = MFMA16(bmf, afr, z4, 0, 0, 0);
    }
    __builtin_amdgcn_s_setprio(0);

    // ---- bias + (diag-only) mask, all in log2 domain ----
    const int dq = q0 + w * 16 + lr - j0;    // qi - j0
    float bq = c_h * (float)(dq - g4 * 4);
    #pragma unroll
    for (int cb = 0; cb < 4; ++cb) {
      float bcb = bq - c16 * (float)cb;
      float sig0 = rcpf(1.f + ex2(-md4[cb][0]));
      float sig1 = rcpf(1.f + ex2(-md4[cb][1]));
      float sig2 = rcpf(1.f + ex2(-md4[cb][2]));
      float sig3 = rcpf(1.f + ex2(-md4[cb][3]));
      acc_s[cb][0] = fmaf(acc_s[cb][0], sc, fmaf(gate, sig0, bcb));
      acc_s[cb][1] = fmaf(acc_s[cb][1], sc, fmaf(gate, sig1, bcb - chr1));
      acc_s[cb][2] = fmaf(acc_s[cb][2], sc, fmaf(gate, sig2, bcb - chr2));
      acc_s[cb][3] = fmaf(acc_s[cb][3], sc, fmaf(gate, sig3, bcb - chr3));
    }
    if (jt == qt) {   // causal mask needed only on the diagonal tile
      #pragma unroll
      for (int cb = 0; cb < 4; ++cb)
        #pragma unroll
        for (int r = 0; r < 4; ++r)
          if (cb * 16 + g4 * 4 + r > dq) acc_s[cb][r] = -INFINITY;
    }

    // ---- online softmax, defer-max (THR = 8*log2e) ----
    float t0 = fmaxf(fmaxf(acc_s[0][0], acc_s[0][1]), acc_s[0][2]);
    float t1 = fmaxf(fmaxf(acc_s[0][3], acc_s[1][0]), acc_s[1][1]);
    float t2 = fmaxf(fmaxf(acc_s[1][2], acc_s[1][3]), acc_s[2][0]);
    float t3 = fmaxf(fmaxf(acc_s[2][1], acc_s[2][2]), acc_s[2][3]);
    float t4 = fmaxf(fmaxf(acc_s[3][0], acc_s[3][1]), acc_s[3][2]);
    float mx = fmaxf(fmaxf(fmaxf(t0, t1), t2),
                     fmaxf(fmaxf(t3, t4), acc_s[3][3]));
    mx = fmaxf(mx, __shfl_xor(mx, 16));
    mx = fmaxf(mx, __shfl_xor(mx, 32));
    if (!__all(mx - m_st <= 11.5415603f)) {
      float mn = fmaxf(m_st, mx);
      float es = ex2(m_st - mn);   // first tile: exp2(-inf)=0
      l_st *= es;
      m_st = mn;
      float es4[4];
      #pragma unroll
      for (int r = 0; r < 4; ++r) es4[r] = __shfl(es, g4 * 4 + r, 64);
      #pragma unroll
      for (int db = 0; db < 8; ++db)
        #pragma unroll
        for (int r = 0; r < 4; ++r) acc_o[db][r] *= es4[r];
    }
    float rs = 0.f;
    #pragma unroll
    for (int cb = 0; cb < 4; ++cb)
      #pragma unroll
      for (int r = 0; r < 4; ++r) {
        float p = ex2(acc_s[cb][r] - m_st);
        acc_s[cb][r] = p;
        rs += p;
      }
    rs += __shfl_xor(rs, 16);
    rs += __shfl_xor(rs, 32);
    l_st += rs;

    // ---- P -> LDS (v_cvt_pk_bf16_f32); wait V landed (counted vmcnt) ----
    #pragma unroll
    for (int cb = 0; cb < 4; ++cb) {
      uint2 uu;
      uu.x = cvtpk(acc_s[cb][0], acc_s[cb][1]);
      uu.y = cvtpk(acc_s[cb][2], acc_s[cb][3]);
      *(uint2*)(Pw + lr * 128 + ((cb * 32 + g4 * 8) ^ ((lr & 7) << 4))) = uu;
    }
    asm volatile("s_waitcnt lgkmcnt(0)" ::: "memory");
    if (pf) asm volatile("s_waitcnt vmcnt(5)" ::: "memory");
    else    asm volatile("s_waitcnt vmcnt(0)" ::: "memory");
    __builtin_amdgcn_s_barrier();          // V visible to all waves
    __builtin_amdgcn_sched_barrier(0);

    // ---- PV ----
    __builtin_amdgcn_s_setprio(1);
    #pragma unroll
    for (int kk = 0; kk < 2; ++kk) {
      bf16x8 pfr = *(const bf16x8*)(Pw + lr * 128 +
                                    ((kk * 64 + g4 * 16) ^ ((lr & 7) << 4)));
      #pragma unroll
      for (int db = 0; db < 8; ++db) {
        bf16x8 vf = *(const bf16x8*)(Vs + (db * 16 + lr) * 128 +
                                     ((kk * 64 + g4 * 16) ^ ((lr & 7) << 4)));
        acc_o[db] = MFMA16(pfr, vf, acc_o[db], 0, 0, 0);
      }
    }
    __builtin_amdgcn_s_setprio(0);
    __builtin_amdgcn_sched_barrier(0);

    // ---- B dbuf write; drain K[jt+1]; end barrier; then stage V[jt+1] ----
    if (pf) {
      int brow = tid >> 2, bsl = tid & 3;
      *(int4*)(Bnxt + brow * 80 + bsl * 16) = breg;
    }
    asm volatile("s_waitcnt vmcnt(0) lgkmcnt(0)" ::: "memory");
    __builtin_amdgcn_s_barrier();
    if (pf) {
      #pragma unroll
      for (int s = 0; s < 4; ++s) {
        int idx = (w * 4 + s) * 64 + lane;
        int row = idx >> 3, slot = idx & 7;
        gload_lds16(Vh + (size_t)row * 2048 + (j0 + 64) + (slot ^ (row & 7)) * 8,
                    Vs + (w * 4 + s) * 1024);
      }
    }
  }

  // epilogue: normalize, store bf16 AO. acc rows q = g4*4+r, col d = db*16+lr.
  float lrcp[4];
  #pragma unroll
  for (int r = 0; r < 4; ++r) lrcp[r] = 1.f / __shfl(l_st, g4 * 4 + r, 64);
  #pragma unroll
  for (int db = 0; db < 8; ++db)
    #pragma unroll
    for (int r = 0; r < 4; ++r)
      AO[(size_t)(q0 + w * 16 + g4 * 4 + r) * 2048 + h * 128 + db * 16 + lr] =
          f2bf(acc_o[db][r] * lrcp[r]);
}

// ---------------------------------------------------------------------------
// Launch
// ---------------------------------------------------------------------------
extern "C" void kernel_launch(void* const* d_in, const int* in_sizes, int n_in,
                              void* d_out, int out_size, void* d_ws, size_t ws_size,
                              hipStream_t stream) {
  const float* x         = (const float*)d_in[0];
  const float* Wq        = (const float*)d_in[1];
  const float* Wk        = (const float*)d_in[2];
  const float* Wv        = (const float*)d_in[3];
  const float* Wo        = (const float*)d_in[4];
  const float* pol_dir   = (const float*)d_in[5];
  const float* pol_WA    = (const float*)d_in[6];
  const float* pol_WB    = (const float*)d_in[7];
  const float* pol_gate  = (const float*)d_in[8];
  const float* gtp_gamma = (const float*)d_in[9];
  float* out = (float*)d_out;

  char* ws = (char*)d_ws;
  short* Qb   = (short*)(ws);                    // 2048x2048 bf16 = 8 MB
  short* Kb   = (short*)(ws + 8388608);          // 2048x512  bf16 = 2 MB
  short* Vtb  = (short*)(ws + 10485760);         // 512x2048  bf16 = 2 MB (V^T)
  short* Ab   = (short*)(ws + 12582912);         // 2048x32   bf16 = 128 KB
  short* Bb   = (short*)(ws + 12713984);         // 2048x32   bf16 = 128 KB
  short* xb   = (short*)(ws + 12845056);         // 8 MB (reused as Wot after qkv)
  short* Wot  = xb;                              // written by mid_kernel (xb dead)
  short* Wqt  = (short*)(ws + 21233664);         // 8 MB (reused as AO after qkv)
  short* AO   = Wqt;                             // written by attn (Wqt dead)
  short* Wkt  = (short*)(ws + 29622272);         // 2 MB
  short* Wvt  = (short*)(ws + 31719424);         // 2 MB
  short* WABt = (short*)(ws + 33816576);         // 128x2048 bf16 = 512 KB
  // total 34.3 MB

  prep_kernel<<<10368, 256, 0, stream>>>(x, Wq, Wk, Wv, pol_WA, pol_WB,
                                         xb, Wqt, Wkt, Wvt, WABt);
  gemm_qkv_kernel<<<dim3(49, 16), 256, 0, stream>>>(xb, Wqt, Wkt, Wvt, WABt,
                                                    Qb, Kb, Vtb, Ab, Bb);
  mid_kernel<<<14336, 256, 0, stream>>>(Wo, Wot, Qb, Kb);
  attn_kernel<<<dim3(16, 32), 256, 0, stream>>>(Qb, Kb, Vtb, Ab, Bb,
                                                pol_dir, pol_gate, gtp_gamma, AO);
  gemm_out_kernel<<<dim3(32, 16), 256, 0, stream>>>(AO, Wot, out);
}

// Round 10
// 157.327 us; speedup vs baseline: 1.1744x; 1.0744x over previous
//
#include <hip/hip_runtime.h>
#include <math.h>

// ---------------------------------------------------------------------------
// Types / helpers
// ---------------------------------------------------------------------------
typedef short bf16x8 __attribute__((ext_vector_type(8)));   // 8 bf16 (4 VGPRs)
typedef float f32x4  __attribute__((ext_vector_type(4)));

#define MFMA16 __builtin_amdgcn_mfma_f32_16x16x32_bf16
#define LOG2E 1.4426950408889634f

static __device__ __forceinline__ short f2bf(float f) {
  union { float f; unsigned u; } x; x.f = f;
  unsigned r = (x.u + 0x7FFFu + ((x.u >> 16) & 1u)) >> 16;  // RTNE
  return (short)r;
}
static __device__ __forceinline__ unsigned packbf(float a, float b) {
  return (unsigned)(unsigned short)f2bf(a) | ((unsigned)(unsigned short)f2bf(b) << 16);
}
static __device__ __forceinline__ float bf2f(short s) {
  union { unsigned u; float f; } x; x.u = ((unsigned)(unsigned short)s) << 16;
  return x.f;
}
static __device__ __forceinline__ void gload_lds16(const void* g, void* l) {
  __builtin_amdgcn_global_load_lds((const __attribute__((address_space(1))) void*)g,
                                   (__attribute__((address_space(3))) void*)l, 16, 0, 0);
}
static __device__ __forceinline__ float ex2(float x) {
  float r; asm("v_exp_f32 %0, %1" : "=v"(r) : "v"(x)); return r;
}
static __device__ __forceinline__ float rcpf(float x) {
  float r; asm("v_rcp_f32 %0, %1" : "=v"(r) : "v"(x)); return r;
}
static __device__ __forceinline__ unsigned cvtpk(float lo, float hi) {
  unsigned r; asm("v_cvt_pk_bf16_f32 %0, %1, %2" : "=v"(r) : "v"(lo), "v"(hi));
  return r;
}

// ---------------------------------------------------------------------------
// Transpose one 32x32 tile: fp32 in [K][N] -> bf16 out [N][K]
// ---------------------------------------------------------------------------
__device__ __forceinline__ void tr_tile(
    const float* __restrict__ in, short* __restrict__ out,
    int K, int N, int nt, int kt, float (*t)[33])
{
  int n0 = nt * 32, k0 = kt * 32;
  int tx = threadIdx.x & 31, ty = threadIdx.x >> 5;
  #pragma unroll
  for (int i = 0; i < 4; ++i)
    t[ty + 8 * i][tx] = in[(size_t)(k0 + ty + 8 * i) * N + n0 + tx];
  __syncthreads();
  #pragma unroll
  for (int i = 0; i < 4; ++i)
    out[(size_t)(n0 + ty + 8 * i) * K + k0 + tx] = f2bf(t[tx][ty + 8 * i]);
}

// Fused prep: Wq/Wk/Wv/WA/WB transposes + x fp32->bf16 convert. grid 10368.
__global__ __launch_bounds__(256) void prep_kernel(
    const float* __restrict__ x, const float* __restrict__ Wq,
    const float* __restrict__ Wk, const float* __restrict__ Wv,
    const float* __restrict__ WA, const float* __restrict__ WB,
    short* __restrict__ xb, short* __restrict__ Wqt, short* __restrict__ Wkt,
    short* __restrict__ Wvt, short* __restrict__ WABt)
{
  __shared__ float t[32][33];
  int b = blockIdx.x;
  if (b < 4096)       tr_tile(Wq, Wqt, 2048, 2048, b & 63, b >> 6, t);
  else if (b < 5120)  { int c = b - 4096; tr_tile(Wk, Wkt, 2048, 512, c & 15, c >> 4, t); }
  else if (b < 6144)  { int c = b - 5120; tr_tile(Wv, Wvt, 2048, 512, c & 15, c >> 4, t); }
  else if (b < 6208)  { int c = b - 6144; tr_tile(WA, WABt, 2048, 32, 0, c, t); }
  else if (b < 6272)  { int c = b - 6208; tr_tile(WB, WABt + 32 * 2048, 2048, 32, 0, c, t); }
  else {
    int i = (b - 6272) * 256 + threadIdx.x;          // 4096 blocks, 1M float4
    float4 v = ((const float4*)x)[i];
    short4 o; o.x = f2bf(v.x); o.y = f2bf(v.y); o.z = f2bf(v.z); o.w = f2bf(v.w);
    ((short4*)xb)[i] = o;
  }
}

// Fused mid: Wo transpose + RoPE on Q/K. grid 4096 + 10240 = 14336.
__global__ __launch_bounds__(256) void mid_kernel(
    const float* __restrict__ Wo, short* __restrict__ Wot,
    short* __restrict__ Q, short* __restrict__ K)
{
  __shared__ float t[32][33];
  int b = blockIdx.x;
  if (b < 4096) { tr_tile(Wo, Wot, 2048, 2048, b & 63, b >> 6, t); return; }
  int idx = (b - 4096) * 256 + threadIdx.x;   // < 2048*20*64
  int d  = idx & 63;
  int hh = (idx >> 6) % 20;
  int tt = idx / (20 * 64);
  short* base = (hh < 16) ? Q + (size_t)tt * 2048 + hh * 128 + d
                          : K + (size_t)tt * 512 + (hh - 16) * 128 + d;
  float inv = __expf((float)d * -0.14391156831212789f);  // 10000^(-d/64)
  float ang = (float)tt * inv;
  float sn, cs;
  __sincosf(ang, &sn, &cs);
  float x1 = bf2f(base[0]), x2 = bf2f(base[64]);
  base[0]  = f2bf(x1 * cs - x2 * sn);
  base[64] = f2bf(x2 * cs + x1 * sn);
}

// ---------------------------------------------------------------------------
// bf16 MFMA GEMM core, C 128(M)x64(N) tile, BK=64 (half the barriers of
// BK=32; 16 MFMA/wave per phase). SINGLE-buffer LDS, full __syncthreads
// drains (deterministic). 64-k rows are 128 B -> 16-way bank conflict if
// linear; fixed with the pre-swizzled-source idiom (global chunk q^(row&7),
// same XOR on the ds_read index; LDS dest linear for global_load_lds).
// A [M][K], Bt [N][K] bf16. 256 threads, 4 waves 2(M)x2(N); 4x2 frags/wave.
// ---------------------------------------------------------------------------
__device__ __forceinline__ void gemm12864_core(
    const short* __restrict__ A, const short* __restrict__ Bt,
    int m0, int n0, int Kd, short* Asm /*128x64*/, short* Bsm /*64x64*/,
    f32x4 acc[4][2])
{
  const int tid = threadIdx.x;
  const int lane = tid & 63, w = tid >> 6;
  const int lr = lane & 15, g4 = lane >> 4;
  const int wm = w >> 1, wn = w & 1;

  for (int k0 = 0; k0 < Kd; k0 += 64) {
    // A: 1024 16B-chunks (128 rows x 8), 4/thread; dest wave-uniform+lane*16
    #pragma unroll
    for (int s = 0; s < 4; ++s) {
      int c = (s * 4 + w) * 64 + lane;          // 0..1023
      int row = c >> 3, q = c & 7;
      gload_lds16(A + (size_t)(m0 + row) * Kd + k0 + (q ^ (row & 7)) * 8,
                  Asm + c * 8);
    }
    // B: 512 chunks (64 rows x 8), 2/thread
    #pragma unroll
    for (int s = 0; s < 2; ++s) {
      int c = (s * 4 + w) * 64 + lane;          // 0..511
      int row = c >> 3, q = c & 7;
      gload_lds16(Bt + (size_t)(n0 + row) * Kd + k0 + (q ^ (row & 7)) * 8,
                  Bsm + c * 8);
    }
    __syncthreads();                      // drains vmcnt+lgkmcnt (compiler)
    #pragma unroll
    for (int kk = 0; kk < 2; ++kk) {
      bf16x8 af[4], bff[2];
      #pragma unroll
      for (int mi = 0; mi < 4; ++mi) {
        int row = wm * 64 + mi * 16 + lr;       // row&7 == lr&7
        af[mi] = *(const bf16x8*)(Asm + row * 64 +
                                  ((kk * 4 + g4) ^ (lr & 7)) * 8);
      }
      #pragma unroll
      for (int ni = 0; ni < 2; ++ni) {
        int row = wn * 32 + ni * 16 + lr;
        bff[ni] = *(const bf16x8*)(Bsm + row * 64 +
                                   ((kk * 4 + g4) ^ (lr & 7)) * 8);
      }
      #pragma unroll
      for (int mi = 0; mi < 4; ++mi)
        #pragma unroll
        for (int ni = 0; ni < 2; ++ni)
          acc[mi][ni] = MFMA16(af[mi], bff[ni], acc[mi][ni], 0, 0, 0);
    }
    __syncthreads();                      // WAR: reads done before restage
  }
}

// Fused QKV + low-rank AB projection. grid (49, 16).
// bx<32: Q, bx<40: K, bx<48: V (transposed out), bx==48: A|B (one 64-col tile).
// A-projection pre-scaled by log2(e) for exp2-domain attn.
__global__ __launch_bounds__(256, 3) void gemm_qkv_kernel(
    const short* __restrict__ xb, const short* __restrict__ Wqt,
    const short* __restrict__ Wkt, const short* __restrict__ Wvt,
    const short* __restrict__ WABt,
    short* __restrict__ Qb, short* __restrict__ Kb, short* __restrict__ Vtb,
    short* __restrict__ Ab, short* __restrict__ Bb)
{
  __shared__ __align__(16) short Asm[128 * 64];
  __shared__ __align__(16) short Bsm[64 * 64];
  f32x4 acc[4][2];
  #pragma unroll
  for (int i = 0; i < 4; ++i)
    #pragma unroll
    for (int j = 0; j < 2; ++j) acc[i][j] = (f32x4){0.f, 0.f, 0.f, 0.f};

  const int bx = blockIdx.x, by = blockIdx.y;
  const short* Bt; int mode, nl0;
  if (bx < 32)      { Bt = Wqt;  nl0 = bx * 64;        mode = 0; }
  else if (bx < 40) { Bt = Wkt;  nl0 = (bx - 32) * 64; mode = 1; }
  else if (bx < 48) { Bt = Wvt;  nl0 = (bx - 40) * 64; mode = 2; }
  else              { Bt = WABt; nl0 = 0;              mode = 3; }

  gemm12864_core(xb, Bt, by * 128, nl0, 2048, Asm, Bsm, acc);

  const int tid = threadIdx.x, lane = tid & 63, w = tid >> 6;
  const int lr = lane & 15, g4 = lane >> 4, wm = w >> 1, wn = w & 1;
  #pragma unroll
  for (int mi = 0; mi < 4; ++mi) {
    #pragma unroll
    for (int ni = 0; ni < 2; ++ni) {
      int mb = by * 128 + wm * 64 + mi * 16 + g4 * 4;
      int ncl = wn * 32 + ni * 16 + lr;    // 0..63 within tile
      int nc = nl0 + ncl;
      if (mode == 0) {
        #pragma unroll
        for (int r = 0; r < 4; ++r)
          Qb[(size_t)(mb + r) * 2048 + nc] = f2bf(acc[mi][ni][r]);
      } else if (mode == 1) {
        #pragma unroll
        for (int r = 0; r < 4; ++r)
          Kb[(size_t)(mb + r) * 512 + nc] = f2bf(acc[mi][ni][r]);
      } else if (mode == 2) {
        uint2 uu;
        uu.x = packbf(acc[mi][ni][0], acc[mi][ni][1]);
        uu.y = packbf(acc[mi][ni][2], acc[mi][ni][3]);
        *(uint2*)(Vtb + (size_t)nc * 2048 + mb) = uu;   // V^T [512][2048]
      } else {
        #pragma unroll
        for (int r = 0; r < 4; ++r) {
          float sv = acc[mi][ni][r];
          if (ncl < 32) Ab[(size_t)(mb + r) * 32 + ncl] = f2bf(sv * LOG2E);
          else          Bb[(size_t)(mb + r) * 32 + (ncl - 32)] = f2bf(sv);
        }
      }
    }
  }
}

// Output projection: out = AO(bf16) @ Wo -> fp32. grid (32, 16).
__global__ __launch_bounds__(256, 3) void gemm_out_kernel(
    const short* __restrict__ AO, const short* __restrict__ Wot,
    float* __restrict__ out)
{
  __shared__ __align__(16) short Asm[128 * 64];
  __shared__ __align__(16) short Bsm[64 * 64];
  f32x4 acc[4][2];
  #pragma unroll
  for (int i = 0; i < 4; ++i)
    #pragma unroll
    for (int j = 0; j < 2; ++j) acc[i][j] = (f32x4){0.f, 0.f, 0.f, 0.f};

  gemm12864_core(AO, Wot, blockIdx.y * 128, blockIdx.x * 64, 2048, Asm, Bsm, acc);

  const int tid = threadIdx.x, lane = tid & 63, w = tid >> 6;
  const int lr = lane & 15, g4 = lane >> 4, wm = w >> 1, wn = w & 1;
  #pragma unroll
  for (int mi = 0; mi < 4; ++mi)
    #pragma unroll
    for (int ni = 0; ni < 2; ++ni) {
      int mb = blockIdx.y * 128 + wm * 64 + mi * 16 + g4 * 4;
      int nc = blockIdx.x * 64 + wn * 32 + ni * 16 + lr;
      #pragma unroll
      for (int r = 0; r < 4; ++r)
        out[(size_t)(mb + r) * 2048 + nc] = acc[mi][ni][r];
    }
}

// ---------------------------------------------------------------------------
// Flash attention (round-6 version, verbatim — measured good: 75us, no spill).
// bf16 MFMA, exp2-domain softmax. grid (16 heads, 32 y),
// qt = (y<16) ? 31-y : y-16 (balanced pairing). LDS-double-buffered K
// (global_load_lds, pre-swizzled source), single V staged after the end
// barrier (counted vmcnt before PV). LDS 66KB -> 2 blocks/CU.
// ---------------------------------------------------------------------------
__global__ __launch_bounds__(256, 2) void attn_kernel(
    const short* __restrict__ Qg, const short* __restrict__ Kg,
    const short* __restrict__ Vtg, const short* __restrict__ Ag,
    const short* __restrict__ Bg, const float* __restrict__ pol_dir,
    const float* __restrict__ pol_gate, const float* __restrict__ gtp_gamma,
    short* __restrict__ AO)
{
  // layout: Kb0 @0 (16K), Kb1 @16384 (16K, Q overlay), Vs @32768 (16K),
  //         Ps @49152 (8K, A overlay), Bs0 @57344 (5K), Bs1 @62464 (5K)
  __shared__ __align__(16) char lds[67584];
  char* const Vs = lds + 32768;
  char* const Ps = lds + 49152;

  const int tid = threadIdx.x;
  const int lane = tid & 63, w = tid >> 6;
  const int lr = lane & 15, g4 = lane >> 4;
  const int h  = blockIdx.x;
  const int by = blockIdx.y;
  const int qt = (by < 16) ? (31 - by) : (by - 16);   // balanced pairing
  const int q0 = qt * 64;
  const int kvh = h >> 2;
  const short* Kh = Kg + kvh * 128;
  const short* Vh = Vtg + (size_t)(kvh * 128) * 2048;

  float pol   = fminf(fmaxf(pol_dir[h], -1.f), 1.f);
  float gamma = fmaxf(log1pf(__expf(gtp_gamma[h])), 1e-6f);
  float gate  = (1.f / (1.f + __expf(-pol_gate[h]))) * LOG2E;
  const float c_h  = -(pol * (1.f / 4096.f) + gamma) * LOG2E;  // log2-domain
  const float c16  = 16.f * c_h;
  const float chr1 = c_h, chr2 = c_h + c_h, chr3 = chr2 + c_h;
  const float sc = 0.08838834764831845f * LOG2E;   // log2e/sqrt(128)
  const f32x4 z4 = {0.f, 0.f, 0.f, 0.f};

  // ---- prologue: K0/V0 via global_load_lds (pre-swizzled source) ----
  #pragma unroll
  for (int s = 0; s < 4; ++s) {
    int idx = (w * 4 + s) * 64 + lane;
    int row = idx >> 4, slot = idx & 15;
    gload_lds16(Kh + (size_t)row * 512 + (slot ^ (row & 7)) * 8,
                lds + (w * 4 + s) * 1024);
  }
  #pragma unroll
  for (int s = 0; s < 4; ++s) {
    int idx = (w * 4 + s) * 64 + lane;
    int row = idx >> 3, slot = idx & 7;
    gload_lds16(Vh + (size_t)row * 2048 + (slot ^ (row & 7)) * 8,
                Vs + (w * 4 + s) * 1024);
  }
  // Q -> Kb1 overlay (swizzled), A -> Ps overlay, B0 -> Bs0 (reg path)
  #pragma unroll
  for (int s = 0; s < 4; ++s) {
    int c = tid + s * 256;
    int row = c >> 4, sl = c & 15;
    int4 v = *(const int4*)(Qg + (size_t)(q0 + row) * 2048 + h * 128 + sl * 8);
    *(int4*)(lds + 16384 + row * 256 + ((sl * 16) ^ ((row & 7) << 4))) = v;
  }
  {
    int row = tid >> 2, sl = tid & 3;
    int4 va = *(const int4*)(Ag + (size_t)(q0 + row) * 32 + sl * 8);
    *(int4*)(Ps + row * 80 + sl * 16) = va;
    int4 vb = *(const int4*)(Bg + (size_t)row * 32 + sl * 8);
    *(int4*)(lds + 57344 + row * 80 + sl * 16) = vb;
  }
  asm volatile("s_waitcnt vmcnt(0) lgkmcnt(0)" ::: "memory");
  __builtin_amdgcn_s_barrier();

  // hoist Q frags (q-row = w*16+lr) and A frag
  bf16x8 qf[4];
  #pragma unroll
  for (int kk = 0; kk < 4; ++kk)
    qf[kk] = *(const bf16x8*)(lds + 16384 + (w * 16 + lr) * 256 +
                              ((kk * 64 + g4 * 16) ^ ((lr & 7) << 4)));
  bf16x8 afr = *(const bf16x8*)(Ps + (w * 16 + lr) * 80 + g4 * 16);
  asm volatile("s_waitcnt lgkmcnt(0)" ::: "memory");
  __builtin_amdgcn_s_barrier();   // Kb1 + Ps now free for K-dbuf / P

  f32x4 acc_o[8];
  #pragma unroll
  for (int i = 0; i < 8; ++i) acc_o[i] = z4;
  float m_st = -INFINITY, l_st = 0.f;
  char* Pw = Ps + w * 2048;

  for (int jt = 0; jt <= qt; ++jt) {
    const int j0 = jt * 64;
    const bool pf = (jt < qt);
    char* Kcur = lds + ((jt & 1) << 14);
    char* Knxt = lds + (((jt + 1) & 1) << 14);
    char* Bcur = lds + 57344 + (jt & 1) * 5120;
    char* Bnxt = lds + 57344 + ((jt + 1) & 1) * 5120;

    // ---- issue next K tile (LDS dbuf, no VGPR cost) + B reg load ----
    int4 breg;
    if (pf) {
      int brow = tid >> 2, bsl = tid & 3;
      breg = *(const int4*)(Bg + (size_t)(j0 + 64 + brow) * 32 + bsl * 8);
      #pragma unroll
      for (int s = 0; s < 4; ++s) {
        int idx = (w * 4 + s) * 64 + lane;
        int row = idx >> 4, slot = idx & 15;
        gload_lds16(Kh + (size_t)(j0 + 64 + row) * 512 + (slot ^ (row & 7)) * 8,
                    Knxt + (w * 4 + s) * 1024);
      }
    }

    // ---- S^T = K.Q^T, md = Bm.A^T ----
    f32x4 acc_s[4], md4[4];
    __builtin_amdgcn_s_setprio(1);
    #pragma unroll
    for (int cb = 0; cb < 4; ++cb) {
      acc_s[cb] = z4;
      #pragma unroll
      for (int kk = 0; kk < 4; ++kk) {
        bf16x8 kf = *(const bf16x8*)(Kcur + (cb * 16 + lr) * 256 +
                                     ((kk * 64 + g4 * 16) ^ ((lr & 7) << 4)));
        acc_s[cb] = MFMA16(kf, qf[kk], acc_s[cb], 0, 0, 0);
      }
      bf16x8 bmf = *(const bf16x8*)(Bcur + (cb * 16 + lr) * 80 + g4 * 16);
      md4[cb] = MFMA16(bmf, afr, z4, 0, 0, 0);
    }
    __builtin_amdgcn_s_setprio(0);

    // ---- bias + (diag-only) mask, all in log2 domain ----
    const int dq = q0 + w * 16 + lr - j0;    // qi - j0
    float bq = c_h * (float)(dq - g4 * 4);
    #pragma unroll
    for (int cb = 0; cb < 4; ++cb) {
      float bcb = bq - c16 * (float)cb;
      float sig0 = rcpf(1.f + ex2(-md4[cb][0]));
      float sig1 = rcpf(1.f + ex2(-md4[cb][1]));
      float sig2 = rcpf(1.f + ex2(-md4[cb][2]));
      float sig3 = rcpf(1.f + ex2(-md4[cb][3]));
      acc_s[cb][0] = fmaf(acc_s[cb][0], sc, fmaf(gate, sig0, bcb));
      acc_s[cb][1] = fmaf(acc_s[cb][1], sc, fmaf(gate, sig1, bcb - chr1));
      acc_s[cb][2] = fmaf(acc_s[cb][2], sc, fmaf(gate, sig2, bcb - chr2));
      acc_s[cb][3] = fmaf(acc_s[cb][3], sc, fmaf(gate, sig3, bcb - chr3));
    }
    if (jt == qt) {   // causal mask needed only on the diagonal tile
      #pragma unroll
      for (int cb = 0; cb < 4; ++cb)
        #pragma unroll
        for (int r = 0; r < 4; ++r)
          if (cb * 16 + g4 * 4 + r > dq) acc_s[cb][r] = -INFINITY;
    }

    // ---- online softmax, defer-max (THR = 8*log2e) ----
    float t0 = fmaxf(fmaxf(acc_s[0][0], acc_s[0][1]), acc_s[0][2]);
    float t1 = fmaxf(fmaxf(acc_s[0][3], acc_s[1][0]), acc_s[1][1]);
    float t2 = fmaxf(fmaxf(acc_s[1][2], acc_s[1][3]), acc_s[2][0]);
    float t3 = fmaxf(fmaxf(acc_s[2][1], acc_s[2][2]), acc_s[2][3]);
    float t4 = fmaxf(fmaxf(acc_s[3][0], acc_s[3][1]), acc_s[3][2]);
    float mx = fmaxf(fmaxf(fmaxf(t0, t1), t2),
                     fmaxf(fmaxf(t3, t4), acc_s[3][3]));
    mx = fmaxf(mx, __shfl_xor(mx, 16));
    mx = fmaxf(mx, __shfl_xor(mx, 32));
    if (!__all(mx - m_st <= 11.5415603f)) {
      float mn = fmaxf(m_st, mx);
      float es = ex2(m_st - mn);   // first tile: exp2(-inf)=0
      l_st *= es;
      m_st = mn;
      float es4[4];
      #pragma unroll
      for (int r = 0; r < 4; ++r) es4[r] = __shfl(es, g4 * 4 + r, 64);
      #pragma unroll
      for (int db = 0; db < 8; ++db)
        #pragma unroll
        for (int r = 0; r < 4; ++r) acc_o[db][r] *= es4[r];
    }
    float rs = 0.f;
    #pragma unroll
    for (int cb = 0; cb < 4; ++cb)
      #pragma unroll
      for (int r = 0; r < 4; ++r) {
        float p = ex2(acc_s[cb][r] - m_st);
        acc_s[cb][r] = p;
        rs += p;
      }
    rs += __shfl_xor(rs, 16);
    rs += __shfl_xor(rs, 32);
    l_st += rs;

    // ---- P -> LDS (v_cvt_pk_bf16_f32); wait V landed (counted vmcnt) ----
    #pragma unroll
    for (int cb = 0; cb < 4; ++cb) {
      uint2 uu;
      uu.x = cvtpk(acc_s[cb][0], acc_s[cb][1]);
      uu.y = cvtpk(acc_s[cb][2], acc_s[cb][3]);
      *(uint2*)(Pw + lr * 128 + ((cb * 32 + g4 * 8) ^ ((lr & 7) << 4))) = uu;
    }
    asm volatile("s_waitcnt lgkmcnt(0)" ::: "memory");
    if (pf) asm volatile("s_waitcnt vmcnt(5)" ::: "memory");
    else    asm volatile("s_waitcnt vmcnt(0)" ::: "memory");
    __builtin_amdgcn_s_barrier();          // V visible to all waves
    __builtin_amdgcn_sched_barrier(0);

    // ---- PV ----
    __builtin_amdgcn_s_setprio(1);
    #pragma unroll
    for (int kk = 0; kk < 2; ++kk) {
      bf16x8 pfr = *(const bf16x8*)(Pw + lr * 128 +
                                    ((kk * 64 + g4 * 16) ^ ((lr & 7) << 4)));
      #pragma unroll
      for (int db = 0; db < 8; ++db) {
        bf16x8 vf = *(const bf16x8*)(Vs + (db * 16 + lr) * 128 +
                                     ((kk * 64 + g4 * 16) ^ ((lr & 7) << 4)));
        acc_o[db] = MFMA16(pfr, vf, acc_o[db], 0, 0, 0);
      }
    }
    __builtin_amdgcn_s_setprio(0);
    __builtin_amdgcn_sched_barrier(0);

    // ---- B dbuf write; drain K[jt+1]; end barrier; then stage V[jt+1] ----
    if (pf) {
      int brow = tid >> 2, bsl = tid & 3;
      *(int4*)(Bnxt + brow * 80 + bsl * 16) = breg;
    }
    asm volatile("s_waitcnt vmcnt(0) lgkmcnt(0)" ::: "memory");
    __builtin_amdgcn_s_barrier();
    if (pf) {
      #pragma unroll
      for (int s = 0; s < 4; ++s) {
        int idx = (w * 4 + s) * 64 + lane;
        int row = idx >> 3, slot = idx & 7;
        gload_lds16(Vh + (size_t)row * 2048 + (j0 + 64) + (slot ^ (row & 7)) * 8,
                    Vs + (w * 4 + s) * 1024);
      }
    }
  }

  // epilogue: normalize, store bf16 AO. acc rows q = g4*4+r, col d = db*16+lr.
  float lrcp[4];
  #pragma unroll
  for (int r = 0; r < 4; ++r) lrcp[r] = 1.f / __shfl(l_st, g4 * 4 + r, 64);
  #pragma unroll
  for (int db = 0; db < 8; ++db)
    #pragma unroll
    for (int r = 0; r < 4; ++r)
      AO[(size_t)(q0 + w * 16 + g4 * 4 + r) * 2048 + h * 128 + db * 16 + lr] =
          f2bf(acc_o[db][r] * lrcp[r]);
}

// ---------------------------------------------------------------------------
// Launch
// ---------------------------------------------------------------------------
extern "C" void kernel_launch(void* const* d_in, const int* in_sizes, int n_in,
                              void* d_out, int out_size, void* d_ws, size_t ws_size,
                              hipStream_t stream) {
  const float* x         = (const float*)d_in[0];
  const float* Wq        = (const float*)d_in[1];
  const float* Wk        = (const float*)d_in[2];
  const float* Wv        = (const float*)d_in[3];
  const float* Wo        = (const float*)d_in[4];
  const float* pol_dir   = (const float*)d_in[5];
  const float* pol_WA    = (const float*)d_in[6];
  const float* pol_WB    = (const float*)d_in[7];
  const float* pol_gate  = (const float*)d_in[8];
  const float* gtp_gamma = (const float*)d_in[9];
  float* out = (float*)d_out;

  char* ws = (char*)d_ws;
  short* Qb   = (short*)(ws);                    // 2048x2048 bf16 = 8 MB
  short* Kb   = (short*)(ws + 8388608);          // 2048x512  bf16 = 2 MB
  short* Vtb  = (short*)(ws + 10485760);         // 512x2048  bf16 = 2 MB (V^T)
  short* Ab   = (short*)(ws + 12582912);         // 2048x32   bf16 = 128 KB
  short* Bb   = (short*)(ws + 12713984);         // 2048x32   bf16 = 128 KB
  short* xb   = (short*)(ws + 12845056);         // 8 MB (reused as Wot after qkv)
  short* Wot  = xb;                              // written by mid_kernel (xb dead)
  short* Wqt  = (short*)(ws + 21233664);         // 8 MB (reused as AO after qkv)
  short* AO   = Wqt;                             // written by attn (Wqt dead)
  short* Wkt  = (short*)(ws + 29622272);         // 2 MB
  short* Wvt  = (short*)(ws + 31719424);         // 2 MB
  short* WABt = (short*)(ws + 33816576);         // 128x2048 bf16 = 512 KB
  // total 34.3 MB

  prep_kernel<<<10368, 256, 0, stream>>>(x, Wq, Wk, Wv, pol_WA, pol_WB,
                                         xb, Wqt, Wkt, Wvt, WABt);
  gemm_qkv_kernel<<<dim3(49, 16), 256, 0, stream>>>(xb, Wqt, Wkt, Wvt, WABt,
                                                    Qb, Kb, Vtb, Ab, Bb);
  mid_kernel<<<14336, 256, 0, stream>>>(Wo, Wot, Qb, Kb);
  attn_kernel<<<dim3(16, 32), 256, 0, stream>>>(Qb, Kb, Vtb, Ab, Bb,
                                                pol_dir, pol_gate, gtp_gamma, AO);
  gemm_out_kernel<<<dim3(32, 16), 256, 0, stream>>>(AO, Wot, out);
}

// Round 11
// 156.884 us; speedup vs baseline: 1.1777x; 1.0028x over previous
//
#include <hip/hip_runtime.h>
#include <math.h>

// ---------------------------------------------------------------------------
// Types / helpers
// ---------------------------------------------------------------------------
typedef short bf16x8 __attribute__((ext_vector_type(8)));   // 8 bf16 (4 VGPRs)
typedef float f32x4  __attribute__((ext_vector_type(4)));

#define MFMA16 __builtin_amdgcn_mfma_f32_16x16x32_bf16
#define LOG2E 1.4426950408889634f

static __device__ __forceinline__ short f2bf(float f) {
  union { float f; unsigned u; } x; x.f = f;
  unsigned r = (x.u + 0x7FFFu + ((x.u >> 16) & 1u)) >> 16;  // RTNE
  return (short)r;
}
static __device__ __forceinline__ unsigned packbf(float a, float b) {
  return (unsigned)(unsigned short)f2bf(a) | ((unsigned)(unsigned short)f2bf(b) << 16);
}
static __device__ __forceinline__ float bf2f(short s) {
  union { unsigned u; float f; } x; x.u = ((unsigned)(unsigned short)s) << 16;
  return x.f;
}
static __device__ __forceinline__ void gload_lds16(const void* g, void* l) {
  __builtin_amdgcn_global_load_lds((const __attribute__((address_space(1))) void*)g,
                                   (__attribute__((address_space(3))) void*)l, 16, 0, 0);
}
static __device__ __forceinline__ float ex2(float x) {
  float r; asm("v_exp_f32 %0, %1" : "=v"(r) : "v"(x)); return r;
}
static __device__ __forceinline__ float rcpf(float x) {
  float r; asm("v_rcp_f32 %0, %1" : "=v"(r) : "v"(x)); return r;
}
static __device__ __forceinline__ unsigned cvtpk(float lo, float hi) {
  unsigned r; asm("v_cvt_pk_bf16_f32 %0, %1, %2" : "=v"(r) : "v"(lo), "v"(hi));
  return r;
}

// ---------------------------------------------------------------------------
// Transpose one 32x32 tile: fp32 in [K][N] -> bf16 out [N][K]
// ---------------------------------------------------------------------------
__device__ __forceinline__ void tr_tile(
    const float* __restrict__ in, short* __restrict__ out,
    int K, int N, int nt, int kt, float (*t)[33])
{
  int n0 = nt * 32, k0 = kt * 32;
  int tx = threadIdx.x & 31, ty = threadIdx.x >> 5;
  #pragma unroll
  for (int i = 0; i < 4; ++i)
    t[ty + 8 * i][tx] = in[(size_t)(k0 + ty + 8 * i) * N + n0 + tx];
  __syncthreads();
  #pragma unroll
  for (int i = 0; i < 4; ++i)
    out[(size_t)(n0 + ty + 8 * i) * K + k0 + tx] = f2bf(t[tx][ty + 8 * i]);
}

// Fused prep: Wq/Wk/Wv/WA/WB transposes + x fp32->bf16 convert. grid 10368.
__global__ __launch_bounds__(256) void prep_kernel(
    const float* __restrict__ x, const float* __restrict__ Wq,
    const float* __restrict__ Wk, const float* __restrict__ Wv,
    const float* __restrict__ WA, const float* __restrict__ WB,
    short* __restrict__ xb, short* __restrict__ Wqt, short* __restrict__ Wkt,
    short* __restrict__ Wvt, short* __restrict__ WABt)
{
  __shared__ float t[32][33];
  int b = blockIdx.x;
  if (b < 4096)       tr_tile(Wq, Wqt, 2048, 2048, b & 63, b >> 6, t);
  else if (b < 5120)  { int c = b - 4096; tr_tile(Wk, Wkt, 2048, 512, c & 15, c >> 4, t); }
  else if (b < 6144)  { int c = b - 5120; tr_tile(Wv, Wvt, 2048, 512, c & 15, c >> 4, t); }
  else if (b < 6208)  { int c = b - 6144; tr_tile(WA, WABt, 2048, 32, 0, c, t); }
  else if (b < 6272)  { int c = b - 6208; tr_tile(WB, WABt + 32 * 2048, 2048, 32, 0, c, t); }
  else {
    int i = (b - 6272) * 256 + threadIdx.x;          // 4096 blocks, 1M float4
    float4 v = ((const float4*)x)[i];
    short4 o; o.x = f2bf(v.x); o.y = f2bf(v.y); o.z = f2bf(v.z); o.w = f2bf(v.w);
    ((short4*)xb)[i] = o;
  }
}

// Fused mid: Wo transpose + RoPE on Q/K. grid 4096 + 10240 = 14336.
__global__ __launch_bounds__(256) void mid_kernel(
    const float* __restrict__ Wo, short* __restrict__ Wot,
    short* __restrict__ Q, short* __restrict__ K)
{
  __shared__ float t[32][33];
  int b = blockIdx.x;
  if (b < 4096) { tr_tile(Wo, Wot, 2048, 2048, b & 63, b >> 6, t); return; }
  int idx = (b - 4096) * 256 + threadIdx.x;   // < 2048*20*64
  int d  = idx & 63;
  int hh = (idx >> 6) % 20;
  int tt = idx / (20 * 64);
  short* base = (hh < 16) ? Q + (size_t)tt * 2048 + hh * 128 + d
                          : K + (size_t)tt * 512 + (hh - 16) * 128 + d;
  float inv = __expf((float)d * -0.14391156831212789f);  // 10000^(-d/64)
  float ang = (float)tt * inv;
  float sn, cs;
  __sincosf(ang, &sn, &cs);
  float x1 = bf2f(base[0]), x2 = bf2f(base[64]);
  base[0]  = f2bf(x1 * cs - x2 * sn);
  base[64] = f2bf(x2 * cs + x1 * sn);
}

// ---------------------------------------------------------------------------
// bf16 MFMA GEMM core, C 128(M)x64(N) tile, BK=64, single-buffer LDS with
// full __syncthreads drains (measured good r10). Pre-swizzled-source idiom
// for the 128B-row bank conflict.
// ---------------------------------------------------------------------------
__device__ __forceinline__ void gemm12864_core(
    const short* __restrict__ A, const short* __restrict__ Bt,
    int m0, int n0, int Kd, short* Asm /*128x64*/, short* Bsm /*64x64*/,
    f32x4 acc[4][2])
{
  const int tid = threadIdx.x;
  const int lane = tid & 63, w = tid >> 6;
  const int lr = lane & 15, g4 = lane >> 4;
  const int wm = w >> 1, wn = w & 1;

  for (int k0 = 0; k0 < Kd; k0 += 64) {
    #pragma unroll
    for (int s = 0; s < 4; ++s) {
      int c = (s * 4 + w) * 64 + lane;          // 0..1023
      int row = c >> 3, q = c & 7;
      gload_lds16(A + (size_t)(m0 + row) * Kd + k0 + (q ^ (row & 7)) * 8,
                  Asm + c * 8);
    }
    #pragma unroll
    for (int s = 0; s < 2; ++s) {
      int c = (s * 4 + w) * 64 + lane;          // 0..511
      int row = c >> 3, q = c & 7;
      gload_lds16(Bt + (size_t)(n0 + row) * Kd + k0 + (q ^ (row & 7)) * 8,
                  Bsm + c * 8);
    }
    __syncthreads();
    #pragma unroll
    for (int kk = 0; kk < 2; ++kk) {
      bf16x8 af[4], bff[2];
      #pragma unroll
      for (int mi = 0; mi < 4; ++mi) {
        int row = wm * 64 + mi * 16 + lr;       // row&7 == lr&7
        af[mi] = *(const bf16x8*)(Asm + row * 64 +
                                  ((kk * 4 + g4) ^ (lr & 7)) * 8);
      }
      #pragma unroll
      for (int ni = 0; ni < 2; ++ni) {
        int row = wn * 32 + ni * 16 + lr;
        bff[ni] = *(const bf16x8*)(Bsm + row * 64 +
                                   ((kk * 4 + g4) ^ (lr & 7)) * 8);
      }
      #pragma unroll
      for (int mi = 0; mi < 4; ++mi)
        #pragma unroll
        for (int ni = 0; ni < 2; ++ni)
          acc[mi][ni] = MFMA16(af[mi], bff[ni], acc[mi][ni], 0, 0, 0);
    }
    __syncthreads();
  }
}

// Fused QKV + low-rank AB projection. grid 784 (1D, XCD-swizzled: 784=8x98).
// bx<32: Q, bx<40: K, bx<48: V (transposed out), bx==48: A|B.
__global__ __launch_bounds__(256, 3) void gemm_qkv_kernel(
    const short* __restrict__ xb, const short* __restrict__ Wqt,
    const short* __restrict__ Wkt, const short* __restrict__ Wvt,
    const short* __restrict__ WABt,
    short* __restrict__ Qb, short* __restrict__ Kb, short* __restrict__ Vtb,
    short* __restrict__ Ab, short* __restrict__ Bb)
{
  __shared__ __align__(16) short Asm[128 * 64];
  __shared__ __align__(16) short Bsm[64 * 64];
  f32x4 acc[4][2];
  #pragma unroll
  for (int i = 0; i < 4; ++i)
    #pragma unroll
    for (int j = 0; j < 2; ++j) acc[i][j] = (f32x4){0.f, 0.f, 0.f, 0.f};

  // T1 XCD swizzle: consecutive blockIdx round-robin XCDs; give each XCD a
  // contiguous chunk of 98 = 2 full by-panels -> A-panel L2-resident.
  const int bid = (int)blockIdx.x;                 // 0..783
  const int swz = (bid & 7) * 98 + (bid >> 3);
  const int bx = swz % 49, by = swz / 49;

  const short* Bt; int mode, nl0;
  if (bx < 32)      { Bt = Wqt;  nl0 = bx * 64;        mode = 0; }
  else if (bx < 40) { Bt = Wkt;  nl0 = (bx - 32) * 64; mode = 1; }
  else if (bx < 48) { Bt = Wvt;  nl0 = (bx - 40) * 64; mode = 2; }
  else              { Bt = WABt; nl0 = 0;              mode = 3; }

  gemm12864_core(xb, Bt, by * 128, nl0, 2048, Asm, Bsm, acc);

  const int tid = threadIdx.x, lane = tid & 63, w = tid >> 6;
  const int lr = lane & 15, g4 = lane >> 4, wm = w >> 1, wn = w & 1;
  #pragma unroll
  for (int mi = 0; mi < 4; ++mi) {
    #pragma unroll
    for (int ni = 0; ni < 2; ++ni) {
      int mb = by * 128 + wm * 64 + mi * 16 + g4 * 4;
      int ncl = wn * 32 + ni * 16 + lr;    // 0..63 within tile
      int nc = nl0 + ncl;
      if (mode == 0) {
        #pragma unroll
        for (int r = 0; r < 4; ++r)
          Qb[(size_t)(mb + r) * 2048 + nc] = f2bf(acc[mi][ni][r]);
      } else if (mode == 1) {
        #pragma unroll
        for (int r = 0; r < 4; ++r)
          Kb[(size_t)(mb + r) * 512 + nc] = f2bf(acc[mi][ni][r]);
      } else if (mode == 2) {
        uint2 uu;
        uu.x = packbf(acc[mi][ni][0], acc[mi][ni][1]);
        uu.y = packbf(acc[mi][ni][2], acc[mi][ni][3]);
        *(uint2*)(Vtb + (size_t)nc * 2048 + mb) = uu;   // V^T [512][2048]
      } else {
        #pragma unroll
        for (int r = 0; r < 4; ++r) {
          float sv = acc[mi][ni][r];
          if (ncl < 32) Ab[(size_t)(mb + r) * 32 + ncl] = f2bf(sv * LOG2E);
          else          Bb[(size_t)(mb + r) * 32 + (ncl - 32)] = f2bf(sv);
        }
      }
    }
  }
}

// Output projection: out = AO(bf16) @ Wo -> fp32. grid 512 (1D, 512=8x64).
__global__ __launch_bounds__(256, 3) void gemm_out_kernel(
    const short* __restrict__ AO, const short* __restrict__ Wot,
    float* __restrict__ out)
{
  __shared__ __align__(16) short Asm[128 * 64];
  __shared__ __align__(16) short Bsm[64 * 64];
  f32x4 acc[4][2];
  #pragma unroll
  for (int i = 0; i < 4; ++i)
    #pragma unroll
    for (int j = 0; j < 2; ++j) acc[i][j] = (f32x4){0.f, 0.f, 0.f, 0.f};

  const int bid = (int)blockIdx.x;                 // 0..511
  const int swz = (bid & 7) * 64 + (bid >> 3);
  const int bx = swz % 32, by = swz / 32;

  gemm12864_core(AO, Wot, by * 128, bx * 64, 2048, Asm, Bsm, acc);

  const int tid = threadIdx.x, lane = tid & 63, w = tid >> 6;
  const int lr = lane & 15, g4 = lane >> 4, wm = w >> 1, wn = w & 1;
  #pragma unroll
  for (int mi = 0; mi < 4; ++mi)
    #pragma unroll
    for (int ni = 0; ni < 2; ++ni) {
      int mb = by * 128 + wm * 64 + mi * 16 + g4 * 4;
      int nc = bx * 64 + wn * 32 + ni * 16 + lr;
      #pragma unroll
      for (int r = 0; r < 4; ++r)
        out[(size_t)(mb + r) * 2048 + nc] = acc[mi][ni][r];
    }
}

// ---------------------------------------------------------------------------
// Flash attention, restructured sync: K AND V LDS-double-buffered, B in
// register double-buffer (bA/bB named sets, even/odd unrolled — no dynamic
// reg indexing). Per tile: [issue K,V,B for jt+1 = 12 vmem] -> vmcnt(12) ->
// barrier -> QK -> softmax -> P(own-wave) -> PV -> barrier. Two barriers,
// one counted wait, NO full drains in the loop.
// LDS 72KB: K0@0 K1@16K V0@32K V1@48K P@64K -> 2 blocks/CU.
// grid (16 heads, 32 y), qt = (y<16)?31-y:y-16 (balanced pairing).
// ---------------------------------------------------------------------------
__global__ __launch_bounds__(256, 2) void attn_kernel(
    const short* __restrict__ Qg, const short* __restrict__ Kg,
    const short* __restrict__ Vtg, const short* __restrict__ Ag,
    const short* __restrict__ Bg, const float* __restrict__ pol_dir,
    const float* __restrict__ pol_gate, const float* __restrict__ gtp_gamma,
    short* __restrict__ AO)
{
  __shared__ __align__(16) char lds[73728];
  char* const K0s = lds;
  char* const K1s = lds + 16384;
  char* const V0s = lds + 32768;
  char* const V1s = lds + 49152;
  char* const Pb  = lds + 65536;   // 8K; A overlay uses first 5120B

  const int tid = threadIdx.x;
  const int lane = tid & 63, w = tid >> 6;
  const int lr = lane & 15, g4 = lane >> 4;
  const int h  = blockIdx.x;
  const int by = blockIdx.y;
  const int qt = (by < 16) ? (31 - by) : (by - 16);   // balanced pairing
  const int q0 = qt * 64;
  const int kvh = h >> 2;
  const short* Kh = Kg + kvh * 128;
  const short* Vh = Vtg + (size_t)(kvh * 128) * 2048;

  float pol   = fminf(fmaxf(pol_dir[h], -1.f), 1.f);
  float gamma = fmaxf(log1pf(__expf(gtp_gamma[h])), 1e-6f);
  float gate  = (1.f / (1.f + __expf(-pol_gate[h]))) * LOG2E;
  const float c_h  = -(pol * (1.f / 4096.f) + gamma) * LOG2E;  // log2-domain
  const float c16  = 16.f * c_h;
  const float chr1 = c_h, chr2 = c_h + c_h, chr3 = chr2 + c_h;
  const float sc = 0.08838834764831845f * LOG2E;   // log2e/sqrt(128)
  const f32x4 z4 = {0.f, 0.f, 0.f, 0.f};

  // ---- prologue: issue K0/V0 (gload_lds) + B0 (regs) = 12 vmem ----
  #pragma unroll
  for (int s = 0; s < 4; ++s) {
    int idx = (w * 4 + s) * 64 + lane;
    int row = idx >> 4, slot = idx & 15;
    gload_lds16(Kh + (size_t)row * 512 + (slot ^ (row & 7)) * 8,
                K0s + (w * 4 + s) * 1024);
  }
  #pragma unroll
  for (int s = 0; s < 4; ++s) {
    int idx = (w * 4 + s) * 64 + lane;
    int row = idx >> 3, slot = idx & 7;
    gload_lds16(Vh + (size_t)row * 2048 + (slot ^ (row & 7)) * 8,
                V0s + (w * 4 + s) * 1024);
  }
  bf16x8 bA0, bA1, bA2, bA3, bB0, bB1, bB2, bB3;
  bA0 = *(const bf16x8*)(Bg + (size_t)(0 * 16 + lr) * 32 + g4 * 8);
  bA1 = *(const bf16x8*)(Bg + (size_t)(1 * 16 + lr) * 32 + g4 * 8);
  bA2 = *(const bf16x8*)(Bg + (size_t)(2 * 16 + lr) * 32 + g4 * 8);
  bA3 = *(const bf16x8*)(Bg + (size_t)(3 * 16 + lr) * 32 + g4 * 8);

  // ---- Q -> K1 overlay (swizzled), A -> P overlay (ds_write path) ----
  #pragma unroll
  for (int s = 0; s < 4; ++s) {
    int c = tid + s * 256;
    int row = c >> 4, sl = c & 15;
    int4 v = *(const int4*)(Qg + (size_t)(q0 + row) * 2048 + h * 128 + sl * 8);
    *(int4*)(K1s + row * 256 + ((sl * 16) ^ ((row & 7) << 4))) = v;
  }
  {
    int row = tid >> 2, sl = tid & 3;
    int4 va = *(const int4*)(Ag + (size_t)(q0 + row) * 32 + sl * 8);
    *(int4*)(Pb + row * 80 + sl * 16) = va;
  }
  asm volatile("s_waitcnt lgkmcnt(0)" ::: "memory");
  __builtin_amdgcn_s_barrier();

  // hoist Q frags (q-row = w*16+lr) and A frag
  bf16x8 qf[4];
  #pragma unroll
  for (int kk = 0; kk < 4; ++kk)
    qf[kk] = *(const bf16x8*)(K1s + (w * 16 + lr) * 256 +
                              ((kk * 64 + g4 * 16) ^ ((lr & 7) << 4)));
  bf16x8 afr = *(const bf16x8*)(Pb + (w * 16 + lr) * 80 + g4 * 16);
  asm volatile("s_waitcnt lgkmcnt(0)" ::: "memory");
  __builtin_amdgcn_s_barrier();   // K1/P overlays now dead (K0/V0/B0 in flight)

  f32x4 acc_o[8];
  #pragma unroll
  for (int i = 0; i < 8; ++i) acc_o[i] = z4;
  float m_st = -INFINITY, l_st = 0.f;
  char* const Pw = Pb + w * 2048;

// One KV tile. KC/VC: current buffers; KN/VN: stage targets; BCi: current
// B regs; BNi: next B regs (written only under pf).
#define ATTN_TILE(JT, KC, VC, KN, VN, BC0, BC1, BC2, BC3, BN0, BN1, BN2, BN3) \
  do {                                                                        \
    const int j0 = (JT) * 64;                                                 \
    const bool pf = (JT) < qt;                                                \
    if (pf) {                                                                 \
      _Pragma("unroll")                                                       \
      for (int s = 0; s < 4; ++s) {                                           \
        int idx = (w * 4 + s) * 64 + lane;                                    \
        int row = idx >> 4, slot = idx & 15;                                  \
        gload_lds16(Kh + (size_t)(j0 + 64 + row) * 512 + (slot ^ (row & 7)) * 8, \
                    (KN) + (w * 4 + s) * 1024);                               \
      }                                                                       \
      _Pragma("unroll")                                                       \
      for (int s = 0; s < 4; ++s) {                                           \
        int idx = (w * 4 + s) * 64 + lane;                                    \
        int row = idx >> 3, slot = idx & 7;                                   \
        gload_lds16(Vh + (size_t)row * 2048 + (j0 + 64) + (slot ^ (row & 7)) * 8, \
                    (VN) + (w * 4 + s) * 1024);                               \
      }                                                                       \
      BN0 = *(const bf16x8*)(Bg + (size_t)(j0 + 64 + 0 * 16 + lr) * 32 + g4 * 8); \
      BN1 = *(const bf16x8*)(Bg + (size_t)(j0 + 64 + 1 * 16 + lr) * 32 + g4 * 8); \
      BN2 = *(const bf16x8*)(Bg + (size_t)(j0 + 64 + 2 * 16 + lr) * 32 + g4 * 8); \
      BN3 = *(const bf16x8*)(Bg + (size_t)(j0 + 64 + 3 * 16 + lr) * 32 + g4 * 8); \
      asm volatile("s_waitcnt vmcnt(12)" ::: "memory");                       \
    } else {                                                                  \
      asm volatile("s_waitcnt vmcnt(0)" ::: "memory");                        \
    }                                                                         \
    __builtin_amdgcn_s_barrier();  /* K/V/B[JT] visible to all waves */       \
    f32x4 acc_s[4], md4[4];                                                   \
    __builtin_amdgcn_s_setprio(1);                                            \
    _Pragma("unroll")                                                         \
    for (int cb = 0; cb < 4; ++cb) {                                          \
      acc_s[cb] = z4;                                                         \
      _Pragma("unroll")                                                       \
      for (int kk = 0; kk < 4; ++kk) {                                        \
        bf16x8 kf = *(const bf16x8*)((KC) + (cb * 16 + lr) * 256 +            \
                                     ((kk * 64 + g4 * 16) ^ ((lr & 7) << 4)));\
        acc_s[cb] = MFMA16(kf, qf[kk], acc_s[cb], 0, 0, 0);                   \
      }                                                                       \
    }                                                                         \
    md4[0] = MFMA16(BC0, afr, z4, 0, 0, 0);                                   \
    md4[1] = MFMA16(BC1, afr, z4, 0, 0, 0);                                   \
    md4[2] = MFMA16(BC2, afr, z4, 0, 0, 0);                                   \
    md4[3] = MFMA16(BC3, afr, z4, 0, 0, 0);                                   \
    __builtin_amdgcn_s_setprio(0);                                            \
    const int dq = q0 + w * 16 + lr - j0;                                     \
    float bq = c_h * (float)(dq - g4 * 4);                                    \
    _Pragma("unroll")                                                         \
    for (int cb = 0; cb < 4; ++cb) {                                          \
      float bcb = bq - c16 * (float)cb;                                       \
      float sig0 = rcpf(1.f + ex2(-md4[cb][0]));                              \
      float sig1 = rcpf(1.f + ex2(-md4[cb][1]));                              \
      float sig2 = rcpf(1.f + ex2(-md4[cb][2]));                              \
      float sig3 = rcpf(1.f + ex2(-md4[cb][3]));                              \
      acc_s[cb][0] = fmaf(acc_s[cb][0], sc, fmaf(gate, sig0, bcb));           \
      acc_s[cb][1] = fmaf(acc_s[cb][1], sc, fmaf(gate, sig1, bcb - chr1));    \
      acc_s[cb][2] = fmaf(acc_s[cb][2], sc, fmaf(gate, sig2, bcb - chr2));    \
      acc_s[cb][3] = fmaf(acc_s[cb][3], sc, fmaf(gate, sig3, bcb - chr3));    \
    }                                                                         \
    if ((JT) == qt) {                                                         \
      _Pragma("unroll")                                                       \
      for (int cb = 0; cb < 4; ++cb)                                          \
        _Pragma("unroll")                                                     \
        for (int r = 0; r < 4; ++r)                                           \
          if (cb * 16 + g4 * 4 + r > dq) acc_s[cb][r] = -INFINITY;            \
    }                                                                         \
    float t0 = fmaxf(fmaxf(acc_s[0][0], acc_s[0][1]), acc_s[0][2]);           \
    float t1 = fmaxf(fmaxf(acc_s[0][3], acc_s[1][0]), acc_s[1][1]);           \
    float t2 = fmaxf(fmaxf(acc_s[1][2], acc_s[1][3]), acc_s[2][0]);           \
    float t3 = fmaxf(fmaxf(acc_s[2][1], acc_s[2][2]), acc_s[2][3]);           \
    float t4 = fmaxf(fmaxf(acc_s[3][0], acc_s[3][1]), acc_s[3][2]);           \
    float mx = fmaxf(fmaxf(fmaxf(t0, t1), t2),                                \
                     fmaxf(fmaxf(t3, t4), acc_s[3][3]));                      \
    mx = fmaxf(mx, __shfl_xor(mx, 16));                                       \
    mx = fmaxf(mx, __shfl_xor(mx, 32));                                       \
    if (!__all(mx - m_st <= 11.5415603f)) {                                   \
      float mn = fmaxf(m_st, mx);                                             \
      float es = ex2(m_st - mn);                                              \
      l_st *= es;                                                             \
      m_st = mn;                                                              \
      float es4[4];                                                           \
      _Pragma("unroll")                                                       \
      for (int r = 0; r < 4; ++r) es4[r] = __shfl(es, g4 * 4 + r, 64);        \
      _Pragma("unroll")                                                       \
      for (int db = 0; db < 8; ++db)                                          \
        _Pragma("unroll")                                                     \
        for (int r = 0; r < 4; ++r) acc_o[db][r] *= es4[r];                   \
    }                                                                         \
    float rs = 0.f;                                                           \
    _Pragma("unroll")                                                         \
    for (int cb = 0; cb < 4; ++cb)                                            \
      _Pragma("unroll")                                                       \
      for (int r = 0; r < 4; ++r) {                                           \
        float p = ex2(acc_s[cb][r] - m_st);                                   \
        acc_s[cb][r] = p;                                                     \
        rs += p;                                                              \
      }                                                                       \
    rs += __shfl_xor(rs, 16);                                                 \
    rs += __shfl_xor(rs, 32);                                                 \
    l_st += rs;                                                               \
    _Pragma("unroll")                                                         \
    for (int cb = 0; cb < 4; ++cb) {                                          \
      uint2 uu;                                                               \
      uu.x = cvtpk(acc_s[cb][0], acc_s[cb][1]);                               \
      uu.y = cvtpk(acc_s[cb][2], acc_s[cb][3]);                               \
      *(uint2*)(Pw + lr * 128 + ((cb * 32 + g4 * 8) ^ ((lr & 7) << 4))) = uu; \
    }                                                                         \
    asm volatile("s_waitcnt lgkmcnt(0)" ::: "memory");                        \
    __builtin_amdgcn_sched_barrier(0);                                        \
    __builtin_amdgcn_s_setprio(1);                                            \
    _Pragma("unroll")                                                         \
    for (int kk = 0; kk < 2; ++kk) {                                          \
      bf16x8 pfr = *(const bf16x8*)(Pw + lr * 128 +                           \
                                    ((kk * 64 + g4 * 16) ^ ((lr & 7) << 4))); \
      _Pragma("unroll")                                                       \
      for (int db = 0; db < 8; ++db) {                                        \
        bf16x8 vf = *(const bf16x8*)((VC) + (db * 16 + lr) * 128 +            \
                                     ((kk * 64 + g4 * 16) ^ ((lr & 7) << 4)));\
        acc_o[db] = MFMA16(pfr, vf, acc_o[db], 0, 0, 0);                      \
      }                                                                       \
    }                                                                         \
    __builtin_amdgcn_s_setprio(0);                                            \
    asm volatile("s_waitcnt lgkmcnt(0)" ::: "memory");                        \
    __builtin_amdgcn_s_barrier();  /* all waves done reading KC/VC */         \
  } while (0)

  for (int jt = 0; jt <= qt; jt += 2) {
    ATTN_TILE(jt, K0s, V0s, K1s, V1s, bA0, bA1, bA2, bA3, bB0, bB1, bB2, bB3);
    if (jt + 1 <= qt)
      ATTN_TILE(jt + 1, K1s, V1s, K0s, V0s, bB0, bB1, bB2, bB3,
                bA0, bA1, bA2, bA3);
  }
#undef ATTN_TILE

  // epilogue: normalize, store bf16 AO. acc rows q = g4*4+r, col d = db*16+lr.
  float lrcp[4];
  #pragma unroll
  for (int r = 0; r < 4; ++r) lrcp[r] = 1.f / __shfl(l_st, g4 * 4 + r, 64);
  #pragma unroll
  for (int db = 0; db < 8; ++db)
    #pragma unroll
    for (int r = 0; r < 4; ++r)
      AO[(size_t)(q0 + w * 16 + g4 * 4 + r) * 2048 + h * 128 + db * 16 + lr] =
          f2bf(acc_o[db][r] * lrcp[r]);
}

// ---------------------------------------------------------------------------
// Launch
// ---------------------------------------------------------------------------
extern "C" void kernel_launch(void* const* d_in, const int* in_sizes, int n_in,
                              void* d_out, int out_size, void* d_ws, size_t ws_size,
                              hipStream_t stream) {
  const float* x         = (const float*)d_in[0];
  const float* Wq        = (const float*)d_in[1];
  const float* Wk        = (const float*)d_in[2];
  const float* Wv        = (const float*)d_in[3];
  const float* Wo        = (const float*)d_in[4];
  const float* pol_dir   = (const float*)d_in[5];
  const float* pol_WA    = (const float*)d_in[6];
  const float* pol_WB    = (const float*)d_in[7];
  const float* pol_gate  = (const float*)d_in[8];
  const float* gtp_gamma = (const float*)d_in[9];
  float* out = (float*)d_out;

  char* ws = (char*)d_ws;
  short* Qb   = (short*)(ws);                    // 2048x2048 bf16 = 8 MB
  short* Kb   = (short*)(ws + 8388608);          // 2048x512  bf16 = 2 MB
  short* Vtb  = (short*)(ws + 10485760);         // 512x2048  bf16 = 2 MB (V^T)
  short* Ab   = (short*)(ws + 12582912);         // 2048x32   bf16 = 128 KB
  short* Bb   = (short*)(ws + 12713984);         // 2048x32   bf16 = 128 KB
  short* xb   = (short*)(ws + 12845056);         // 8 MB (reused as Wot after qkv)
  short* Wot  = xb;                              // written by mid_kernel (xb dead)
  short* Wqt  = (short*)(ws + 21233664);         // 8 MB (reused as AO after qkv)
  short* AO   = Wqt;                             // written by attn (Wqt dead)
  short* Wkt  = (short*)(ws + 29622272);         // 2 MB
  short* Wvt  = (short*)(ws + 31719424);         // 2 MB
  short* WABt = (short*)(ws + 33816576);         // 128x2048 bf16 = 512 KB
  // total 34.3 MB

  prep_kernel<<<10368, 256, 0, stream>>>(x, Wq, Wk, Wv, pol_WA, pol_WB,
                                         xb, Wqt, Wkt, Wvt, WABt);
  gemm_qkv_kernel<<<784, 256, 0, stream>>>(xb, Wqt, Wkt, Wvt, WABt,
                                           Qb, Kb, Vtb, Ab, Bb);
  mid_kernel<<<14336, 256, 0, stream>>>(Wo, Wot, Qb, Kb);
  attn_kernel<<<dim3(16, 32), 256, 0, stream>>>(Qb, Kb, Vtb, Ab, Bb,
                                                pol_dir, pol_gate, gtp_gamma, AO);
  gemm_out_kernel<<<512, 256, 0, stream>>>(AO, Wot, out);
}

// Round 12
// 150.037 us; speedup vs baseline: 1.2315x; 1.0456x over previous
//
#include <hip/hip_runtime.h>
#include <math.h>

// ---------------------------------------------------------------------------
// Types / helpers
// ---------------------------------------------------------------------------
typedef short bf16x8 __attribute__((ext_vector_type(8)));   // 8 bf16 (4 VGPRs)
typedef float f32x4  __attribute__((ext_vector_type(4)));

#define MFMA16 __builtin_amdgcn_mfma_f32_16x16x32_bf16
#define LOG2E 1.4426950408889634f

static __device__ __forceinline__ short f2bf(float f) {
  union { float f; unsigned u; } x; x.f = f;
  unsigned r = (x.u + 0x7FFFu + ((x.u >> 16) & 1u)) >> 16;  // RTNE
  return (short)r;
}
static __device__ __forceinline__ unsigned packbf(float a, float b) {
  return (unsigned)(unsigned short)f2bf(a) | ((unsigned)(unsigned short)f2bf(b) << 16);
}
static __device__ __forceinline__ float bf2f(short s) {
  union { unsigned u; float f; } x; x.u = ((unsigned)(unsigned short)s) << 16;
  return x.f;
}
static __device__ __forceinline__ void gload_lds16(const void* g, void* l) {
  __builtin_amdgcn_global_load_lds((const __attribute__((address_space(1))) void*)g,
                                   (__attribute__((address_space(3))) void*)l, 16, 0, 0);
}
static __device__ __forceinline__ float ex2(float x) {
  float r; asm("v_exp_f32 %0, %1" : "=v"(r) : "v"(x)); return r;
}
static __device__ __forceinline__ float rcpf(float x) {
  float r; asm("v_rcp_f32 %0, %1" : "=v"(r) : "v"(x)); return r;
}
static __device__ __forceinline__ unsigned cvtpk(float lo, float hi) {
  unsigned r; asm("v_cvt_pk_bf16_f32 %0, %1, %2" : "=v"(r) : "v"(lo), "v"(hi));
  return r;
}

// ---------------------------------------------------------------------------
// Transpose one 32x32 tile: fp32 in [K][N] -> bf16 out [N][K]
// ---------------------------------------------------------------------------
__device__ __forceinline__ void tr_tile(
    const float* __restrict__ in, short* __restrict__ out,
    int K, int N, int nt, int kt, float (*t)[33])
{
  int n0 = nt * 32, k0 = kt * 32;
  int tx = threadIdx.x & 31, ty = threadIdx.x >> 5;
  #pragma unroll
  for (int i = 0; i < 4; ++i)
    t[ty + 8 * i][tx] = in[(size_t)(k0 + ty + 8 * i) * N + n0 + tx];
  __syncthreads();
  #pragma unroll
  for (int i = 0; i < 4; ++i)
    out[(size_t)(n0 + ty + 8 * i) * K + k0 + tx] = f2bf(t[tx][ty + 8 * i]);
}

// Fused prep: Wq/Wk/Wv/WA/WB/Wo transposes + x fp32->bf16 convert. grid 14464.
__global__ __launch_bounds__(256) void prep_kernel(
    const float* __restrict__ x, const float* __restrict__ Wq,
    const float* __restrict__ Wk, const float* __restrict__ Wv,
    const float* __restrict__ WA, const float* __restrict__ WB,
    const float* __restrict__ Wo,
    short* __restrict__ xb, short* __restrict__ Wqt, short* __restrict__ Wkt,
    short* __restrict__ Wvt, short* __restrict__ WABt, short* __restrict__ Wot)
{
  __shared__ float t[32][33];
  int b = blockIdx.x;
  if (b < 4096)       tr_tile(Wq, Wqt, 2048, 2048, b & 63, b >> 6, t);
  else if (b < 5120)  { int c = b - 4096; tr_tile(Wk, Wkt, 2048, 512, c & 15, c >> 4, t); }
  else if (b < 6144)  { int c = b - 5120; tr_tile(Wv, Wvt, 2048, 512, c & 15, c >> 4, t); }
  else if (b < 6208)  { int c = b - 6144; tr_tile(WA, WABt, 2048, 32, 0, c, t); }
  else if (b < 6272)  { int c = b - 6208; tr_tile(WB, WABt + 32 * 2048, 2048, 32, 0, c, t); }
  else if (b < 10368) {
    int i = (b - 6272) * 256 + threadIdx.x;          // 4096 blocks, 1M float4
    float4 v = ((const float4*)x)[i];
    short4 o; o.x = f2bf(v.x); o.y = f2bf(v.y); o.z = f2bf(v.z); o.w = f2bf(v.w);
    ((short4*)xb)[i] = o;
  } else {
    int c = b - 10368;                               // 4096 blocks
    tr_tile(Wo, Wot, 2048, 2048, c & 63, c >> 6, t);
  }
}

// RoPE on K only [2048][512] (4 heads, pairs (d, d+64)). grid 2048.
__global__ __launch_bounds__(256) void ropek_kernel(short* __restrict__ K)
{
  int idx = blockIdx.x * 256 + threadIdx.x;   // < 2048*4*64
  int d  = idx & 63;
  int hh = (idx >> 6) & 3;
  int tt = idx >> 8;
  short* base = K + (size_t)tt * 512 + hh * 128 + d;
  float inv = __expf((float)d * -0.14391156831212789f);  // 10000^(-d/64)
  float ang = (float)tt * inv;
  float sn, cs;
  __sincosf(ang, &sn, &cs);
  float x1 = bf2f(base[0]), x2 = bf2f(base[64]);
  base[0]  = f2bf(x1 * cs - x2 * sn);
  base[64] = f2bf(x2 * cs + x1 * sn);
}

// ---------------------------------------------------------------------------
// bf16 MFMA GEMM core, C 128(M)x64(N) tile, BK=64, single-buffer LDS with
// full __syncthreads drains. Pre-swizzled-source idiom for the 128B-row
// bank conflict. (measured good r10/r11)
// ---------------------------------------------------------------------------
__device__ __forceinline__ void gemm12864_core(
    const short* __restrict__ A, const short* __restrict__ Bt,
    int m0, int n0, int Kd, short* Asm /*128x64*/, short* Bsm /*64x64*/,
    f32x4 acc[4][2])
{
  const int tid = threadIdx.x;
  const int lane = tid & 63, w = tid >> 6;
  const int lr = lane & 15, g4 = lane >> 4;
  const int wm = w >> 1, wn = w & 1;

  for (int k0 = 0; k0 < Kd; k0 += 64) {
    #pragma unroll
    for (int s = 0; s < 4; ++s) {
      int c = (s * 4 + w) * 64 + lane;          // 0..1023
      int row = c >> 3, q = c & 7;
      gload_lds16(A + (size_t)(m0 + row) * Kd + k0 + (q ^ (row & 7)) * 8,
                  Asm + c * 8);
    }
    #pragma unroll
    for (int s = 0; s < 2; ++s) {
      int c = (s * 4 + w) * 64 + lane;          // 0..511
      int row = c >> 3, q = c & 7;
      gload_lds16(Bt + (size_t)(n0 + row) * Kd + k0 + (q ^ (row & 7)) * 8,
                  Bsm + c * 8);
    }
    __syncthreads();
    #pragma unroll
    for (int kk = 0; kk < 2; ++kk) {
      bf16x8 af[4], bff[2];
      #pragma unroll
      for (int mi = 0; mi < 4; ++mi) {
        int row = wm * 64 + mi * 16 + lr;       // row&7 == lr&7
        af[mi] = *(const bf16x8*)(Asm + row * 64 +
                                  ((kk * 4 + g4) ^ (lr & 7)) * 8);
      }
      #pragma unroll
      for (int ni = 0; ni < 2; ++ni) {
        int row = wn * 32 + ni * 16 + lr;
        bff[ni] = *(const bf16x8*)(Bsm + row * 64 +
                                   ((kk * 4 + g4) ^ (lr & 7)) * 8);
      }
      #pragma unroll
      for (int mi = 0; mi < 4; ++mi)
        #pragma unroll
        for (int ni = 0; ni < 2; ++ni)
          acc[mi][ni] = MFMA16(af[mi], bff[ni], acc[mi][ni], 0, 0, 0);
    }
    __syncthreads();
  }
}

// Fused QKV + low-rank AB projection. grid 784 (1D, XCD-swizzled: 784=8x98).
__global__ __launch_bounds__(256, 3) void gemm_qkv_kernel(
    const short* __restrict__ xb, const short* __restrict__ Wqt,
    const short* __restrict__ Wkt, const short* __restrict__ Wvt,
    const short* __restrict__ WABt,
    short* __restrict__ Qb, short* __restrict__ Kb, short* __restrict__ Vtb,
    short* __restrict__ Ab, short* __restrict__ Bb)
{
  __shared__ __align__(16) short Asm[128 * 64];
  __shared__ __align__(16) short Bsm[64 * 64];
  f32x4 acc[4][2];
  #pragma unroll
  for (int i = 0; i < 4; ++i)
    #pragma unroll
    for (int j = 0; j < 2; ++j) acc[i][j] = (f32x4){0.f, 0.f, 0.f, 0.f};

  const int bid = (int)blockIdx.x;                 // 0..783
  const int swz = (bid & 7) * 98 + (bid >> 3);
  const int bx = swz % 49, by = swz / 49;

  const short* Bt; int mode, nl0;
  if (bx < 32)      { Bt = Wqt;  nl0 = bx * 64;        mode = 0; }
  else if (bx < 40) { Bt = Wkt;  nl0 = (bx - 32) * 64; mode = 1; }
  else if (bx < 48) { Bt = Wvt;  nl0 = (bx - 40) * 64; mode = 2; }
  else              { Bt = WABt; nl0 = 0;              mode = 3; }

  gemm12864_core(xb, Bt, by * 128, nl0, 2048, Asm, Bsm, acc);

  const int tid = threadIdx.x, lane = tid & 63, w = tid >> 6;
  const int lr = lane & 15, g4 = lane >> 4, wm = w >> 1, wn = w & 1;
  #pragma unroll
  for (int mi = 0; mi < 4; ++mi) {
    #pragma unroll
    for (int ni = 0; ni < 2; ++ni) {
      int mb = by * 128 + wm * 64 + mi * 16 + g4 * 4;
      int ncl = wn * 32 + ni * 16 + lr;    // 0..63 within tile
      int nc = nl0 + ncl;
      if (mode == 0) {
        #pragma unroll
        for (int r = 0; r < 4; ++r)
          Qb[(size_t)(mb + r) * 2048 + nc] = f2bf(acc[mi][ni][r]);
      } else if (mode == 1) {
        #pragma unroll
        for (int r = 0; r < 4; ++r)
          Kb[(size_t)(mb + r) * 512 + nc] = f2bf(acc[mi][ni][r]);
      } else if (mode == 2) {
        uint2 uu;
        uu.x = packbf(acc[mi][ni][0], acc[mi][ni][1]);
        uu.y = packbf(acc[mi][ni][2], acc[mi][ni][3]);
        *(uint2*)(Vtb + (size_t)nc * 2048 + mb) = uu;   // V^T [512][2048]
      } else {
        #pragma unroll
        for (int r = 0; r < 4; ++r) {
          float sv = acc[mi][ni][r];
          if (ncl < 32) Ab[(size_t)(mb + r) * 32 + ncl] = f2bf(sv * LOG2E);
          else          Bb[(size_t)(mb + r) * 32 + (ncl - 32)] = f2bf(sv);
        }
      }
    }
  }
}

// Output projection: out = AO(bf16) @ Wo -> fp32. grid 512 (1D, 512=8x64).
__global__ __launch_bounds__(256, 3) void gemm_out_kernel(
    const short* __restrict__ AO, const short* __restrict__ Wot,
    float* __restrict__ out)
{
  __shared__ __align__(16) short Asm[128 * 64];
  __shared__ __align__(16) short Bsm[64 * 64];
  f32x4 acc[4][2];
  #pragma unroll
  for (int i = 0; i < 4; ++i)
    #pragma unroll
    for (int j = 0; j < 2; ++j) acc[i][j] = (f32x4){0.f, 0.f, 0.f, 0.f};

  const int bid = (int)blockIdx.x;                 // 0..511
  const int swz = (bid & 7) * 64 + (bid >> 3);
  const int bx = swz % 32, by = swz / 32;

  gemm12864_core(AO, Wot, by * 128, bx * 64, 2048, Asm, Bsm, acc);

  const int tid = threadIdx.x, lane = tid & 63, w = tid >> 6;
  const int lr = lane & 15, g4 = lane >> 4, wm = w >> 1, wn = w & 1;
  #pragma unroll
  for (int mi = 0; mi < 4; ++mi)
    #pragma unroll
    for (int ni = 0; ni < 2; ++ni) {
      int mb = by * 128 + wm * 64 + mi * 16 + g4 * 4;
      int nc = bx * 64 + wn * 32 + ni * 16 + lr;
      #pragma unroll
      for (int r = 0; r < 4; ++r)
        out[(size_t)(mb + r) * 2048 + nc] = acc[mi][ni][r];
    }
}

// ---------------------------------------------------------------------------
// Flash attention — round-6 structure verbatim (measured 74.6us x3) with ONE
// localized edit: Q-RoPE fused into the Q-staging prologue (Q is read by
// exactly one block per element, so RoPE here = same work, saves mid's Q pass).
// bf16 MFMA, exp2-domain softmax. grid (16 heads, 32 y),
// qt = (y<16) ? 31-y : y-16 (balanced pairing). LDS-double-buffered K
// (global_load_lds, pre-swizzled source), single V staged after the end
// barrier (counted vmcnt before PV). LDS 66KB -> 2 blocks/CU.
// ---------------------------------------------------------------------------
__global__ __launch_bounds__(256, 2) void attn_kernel(
    const short* __restrict__ Qg, const short* __restrict__ Kg,
    const short* __restrict__ Vtg, const short* __restrict__ Ag,
    const short* __restrict__ Bg, const float* __restrict__ pol_dir,
    const float* __restrict__ pol_gate, const float* __restrict__ gtp_gamma,
    short* __restrict__ AO)
{
  // layout: Kb0 @0 (16K), Kb1 @16384 (16K, Q overlay), Vs @32768 (16K),
  //         Ps @49152 (8K, A overlay), Bs0 @57344 (5K), Bs1 @62464 (5K)
  __shared__ __align__(16) char lds[67584];
  char* const Vs = lds + 32768;
  char* const Ps = lds + 49152;

  const int tid = threadIdx.x;
  const int lane = tid & 63, w = tid >> 6;
  const int lr = lane & 15, g4 = lane >> 4;
  const int h  = blockIdx.x;
  const int by = blockIdx.y;
  const int qt = (by < 16) ? (31 - by) : (by - 16);   // balanced pairing
  const int q0 = qt * 64;
  const int kvh = h >> 2;
  const short* Kh = Kg + kvh * 128;
  const short* Vh = Vtg + (size_t)(kvh * 128) * 2048;

  float pol   = fminf(fmaxf(pol_dir[h], -1.f), 1.f);
  float gamma = fmaxf(log1pf(__expf(gtp_gamma[h])), 1e-6f);
  float gate  = (1.f / (1.f + __expf(-pol_gate[h]))) * LOG2E;
  const float c_h  = -(pol * (1.f / 4096.f) + gamma) * LOG2E;  // log2-domain
  const float c16  = 16.f * c_h;
  const float chr1 = c_h, chr2 = c_h + c_h, chr3 = chr2 + c_h;
  const float sc = 0.08838834764831845f * LOG2E;   // log2e/sqrt(128)
  const f32x4 z4 = {0.f, 0.f, 0.f, 0.f};

  // ---- prologue: K0/V0 via global_load_lds (pre-swizzled source) ----
  #pragma unroll
  for (int s = 0; s < 4; ++s) {
    int idx = (w * 4 + s) * 64 + lane;
    int row = idx >> 4, slot = idx & 15;
    gload_lds16(Kh + (size_t)row * 512 + (slot ^ (row & 7)) * 8,
                lds + (w * 4 + s) * 1024);
  }
  #pragma unroll
  for (int s = 0; s < 4; ++s) {
    int idx = (w * 4 + s) * 64 + lane;
    int row = idx >> 3, slot = idx & 7;
    gload_lds16(Vh + (size_t)row * 2048 + (slot ^ (row & 7)) * 8,
                Vs + (w * 4 + s) * 1024);
  }
  // Q -> Kb1 overlay (swizzled) WITH FUSED RoPE: job c handles row=c>>3,
  // slot-pair (sl, sl+8) = cols [sl*8, sl*8+8) and [+64). Same formulas as
  // the old rope kernel (bf16 in -> f32 rotate -> bf16 out).
  #pragma unroll
  for (int s = 0; s < 2; ++s) {
    int c = tid + s * 256;            // 0..511
    int row = c >> 3, sl = c & 7;
    const short* qrow = Qg + (size_t)(q0 + row) * 2048 + h * 128;
    int4 vlo = *(const int4*)(qrow + sl * 8);
    int4 vhi = *(const int4*)(qrow + 64 + sl * 8);
    short* lop = (short*)&vlo;
    short* hip = (short*)&vhi;
    short rlo[8], rhi[8];
    float tf = (float)(q0 + row);
    #pragma unroll
    for (int j = 0; j < 8; ++j) {
      int d = sl * 8 + j;
      float inv = __expf((float)d * -0.14391156831212789f);  // 10000^(-d/64)
      float ang = tf * inv;
      float sn, cs;
      __sincosf(ang, &sn, &cs);
      float x1 = bf2f(lop[j]), x2 = bf2f(hip[j]);
      rlo[j] = f2bf(x1 * cs - x2 * sn);
      rhi[j] = f2bf(x2 * cs + x1 * sn);
    }
    *(int4*)(lds + 16384 + row * 256 + ((sl * 16) ^ ((row & 7) << 4))) =
        *(int4*)rlo;
    *(int4*)(lds + 16384 + row * 256 + (((sl + 8) * 16) ^ ((row & 7) << 4))) =
        *(int4*)rhi;
  }
  {
    int row = tid >> 2, sl = tid & 3;
    int4 va = *(const int4*)(Ag + (size_t)(q0 + row) * 32 + sl * 8);
    *(int4*)(Ps + row * 80 + sl * 16) = va;
    int4 vb = *(const int4*)(Bg + (size_t)row * 32 + sl * 8);
    *(int4*)(lds + 57344 + row * 80 + sl * 16) = vb;
  }
  asm volatile("s_waitcnt vmcnt(0) lgkmcnt(0)" ::: "memory");
  __builtin_amdgcn_s_barrier();

  // hoist Q frags (q-row = w*16+lr) and A frag
  bf16x8 qf[4];
  #pragma unroll
  for (int kk = 0; kk < 4; ++kk)
    qf[kk] = *(const bf16x8*)(lds + 16384 + (w * 16 + lr) * 256 +
                              ((kk * 64 + g4 * 16) ^ ((lr & 7) << 4)));
  bf16x8 afr = *(const bf16x8*)(Ps + (w * 16 + lr) * 80 + g4 * 16);
  asm volatile("s_waitcnt lgkmcnt(0)" ::: "memory");
  __builtin_amdgcn_s_barrier();   // Kb1 + Ps now free for K-dbuf / P

  f32x4 acc_o[8];
  #pragma unroll
  for (int i = 0; i < 8; ++i) acc_o[i] = z4;
  float m_st = -INFINITY, l_st = 0.f;
  char* Pw = Ps + w * 2048;

  for (int jt = 0; jt <= qt; ++jt) {
    const int j0 = jt * 64;
    const bool pf = (jt < qt);
    char* Kcur = lds + ((jt & 1) << 14);
    char* Knxt = lds + (((jt + 1) & 1) << 14);
    char* Bcur = lds + 57344 + (jt & 1) * 5120;
    char* Bnxt = lds + 57344 + ((jt + 1) & 1) * 5120;

    // ---- issue next K tile (LDS dbuf, no VGPR cost) + B reg load ----
    int4 breg;
    if (pf) {
      int brow = tid >> 2, bsl = tid & 3;
      breg = *(const int4*)(Bg + (size_t)(j0 + 64 + brow) * 32 + bsl * 8);
      #pragma unroll
      for (int s = 0; s < 4; ++s) {
        int idx = (w * 4 + s) * 64 + lane;
        int row = idx >> 4, slot = idx & 15;
        gload_lds16(Kh + (size_t)(j0 + 64 + row) * 512 + (slot ^ (row & 7)) * 8,
                    Knxt + (w * 4 + s) * 1024);
      }
    }

    // ---- S^T = K.Q^T, md = Bm.A^T ----
    f32x4 acc_s[4], md4[4];
    __builtin_amdgcn_s_setprio(1);
    #pragma unroll
    for (int cb = 0; cb < 4; ++cb) {
      acc_s[cb] = z4;
      #pragma unroll
      for (int kk = 0; kk < 4; ++kk) {
        bf16x8 kf = *(const bf16x8*)(Kcur + (cb * 16 + lr) * 256 +
                                     ((kk * 64 + g4 * 16) ^ ((lr & 7) << 4)));
        acc_s[cb] = MFMA16(kf, qf[kk], acc_s[cb], 0, 0, 0);
      }
      bf16x8 bmf = *(const bf16x8*)(Bcur + (cb * 16 + lr) * 80 + g4 * 16);
      md4[cb] = MFMA16(bmf, afr, z4, 0, 0, 0);
    }
    __builtin_amdgcn_s_setprio(0);

    // ---- bias + (diag-only) mask, all in log2 domain ----
    const int dq = q0 + w * 16 + lr - j0;    // qi - j0
    float bq = c_h * (float)(dq - g4 * 4);
    #pragma unroll
    for (int cb = 0; cb < 4; ++cb) {
      float bcb = bq - c16 * (float)cb;
      float sig0 = rcpf(1.f + ex2(-md4[cb][0]));
      float sig1 = rcpf(1.f + ex2(-md4[cb][1]));
      float sig2 = rcpf(1.f + ex2(-md4[cb][2]));
      float sig3 = rcpf(1.f + ex2(-md4[cb][3]));
      acc_s[cb][0] = fmaf(acc_s[cb][0], sc, fmaf(gate, sig0, bcb));
      acc_s[cb][1] = fmaf(acc_s[cb][1], sc, fmaf(gate, sig1, bcb - chr1));
      acc_s[cb][2] = fmaf(acc_s[cb][2], sc, fmaf(gate, sig2, bcb - chr2));
      acc_s[cb][3] = fmaf(acc_s[cb][3], sc, fmaf(gate, sig3, bcb - chr3));
    }
    if (jt == qt) {   // causal mask needed only on the diagonal tile
      #pragma unroll
      for (int cb = 0; cb < 4; ++cb)
        #pragma unroll
        for (int r = 0; r < 4; ++r)
          if (cb * 16 + g4 * 4 + r > dq) acc_s[cb][r] = -INFINITY;
    }

    // ---- online softmax, defer-max (THR = 8*log2e) ----
    float t0 = fmaxf(fmaxf(acc_s[0][0], acc_s[0][1]), acc_s[0][2]);
    float t1 = fmaxf(fmaxf(acc_s[0][3], acc_s[1][0]), acc_s[1][1]);
    float t2 = fmaxf(fmaxf(acc_s[1][2], acc_s[1][3]), acc_s[2][0]);
    float t3 = fmaxf(fmaxf(acc_s[2][1], acc_s[2][2]), acc_s[2][3]);
    float t4 = fmaxf(fmaxf(acc_s[3][0], acc_s[3][1]), acc_s[3][2]);
    float mx = fmaxf(fmaxf(fmaxf(t0, t1), t2),
                     fmaxf(fmaxf(t3, t4), acc_s[3][3]));
    mx = fmaxf(mx, __shfl_xor(mx, 16));
    mx = fmaxf(mx, __shfl_xor(mx, 32));
    if (!__all(mx - m_st <= 11.5415603f)) {
      float mn = fmaxf(m_st, mx);
      float es = ex2(m_st - mn);   // first tile: exp2(-inf)=0
      l_st *= es;
      m_st = mn;
      float es4[4];
      #pragma unroll
      for (int r = 0; r < 4; ++r) es4[r] = __shfl(es, g4 * 4 + r, 64);
      #pragma unroll
      for (int db = 0; db < 8; ++db)
        #pragma unroll
        for (int r = 0; r < 4; ++r) acc_o[db][r] *= es4[r];
    }
    float rs = 0.f;
    #pragma unroll
    for (int cb = 0; cb < 4; ++cb)
      #pragma unroll
      for (int r = 0; r < 4; ++r) {
        float p = ex2(acc_s[cb][r] - m_st);
        acc_s[cb][r] = p;
        rs += p;
      }
    rs += __shfl_xor(rs, 16);
    rs += __shfl_xor(rs, 32);
    l_st += rs;

    // ---- P -> LDS (v_cvt_pk_bf16_f32); wait V landed (counted vmcnt) ----
    #pragma unroll
    for (int cb = 0; cb < 4; ++cb) {
      uint2 uu;
      uu.x = cvtpk(acc_s[cb][0], acc_s[cb][1]);
      uu.y = cvtpk(acc_s[cb][2], acc_s[cb][3]);
      *(uint2*)(Pw + lr * 128 + ((cb * 32 + g4 * 8) ^ ((lr & 7) << 4))) = uu;
    }
    asm volatile("s_waitcnt lgkmcnt(0)" ::: "memory");
    if (pf) asm volatile("s_waitcnt vmcnt(5)" ::: "memory");
    else    asm volatile("s_waitcnt vmcnt(0)" ::: "memory");
    __builtin_amdgcn_s_barrier();          // V visible to all waves
    __builtin_amdgcn_sched_barrier(0);

    // ---- PV ----
    __builtin_amdgcn_s_setprio(1);
    #pragma unroll
    for (int kk = 0; kk < 2; ++kk) {
      bf16x8 pfr = *(const bf16x8*)(Pw + lr * 128 +
                                    ((kk * 64 + g4 * 16) ^ ((lr & 7) << 4)));
      #pragma unroll
      for (int db = 0; db < 8; ++db) {
        bf16x8 vf = *(const bf16x8*)(Vs + (db * 16 + lr) * 128 +
                                     ((kk * 64 + g4 * 16) ^ ((lr & 7) << 4)));
        acc_o[db] = MFMA16(pfr, vf, acc_o[db], 0, 0, 0);
      }
    }
    __builtin_amdgcn_s_setprio(0);
    __builtin_amdgcn_sched_barrier(0);

    // ---- B dbuf write; drain K[jt+1]; end barrier; then stage V[jt+1] ----
    if (pf) {
      int brow = tid >> 2, bsl = tid & 3;
      *(int4*)(Bnxt + brow * 80 + bsl * 16) = breg;
    }
    asm volatile("s_waitcnt vmcnt(0) lgkmcnt(0)" ::: "memory");
    __builtin_amdgcn_s_barrier();
    if (pf) {
      #pragma unroll
      for (int s = 0; s < 4; ++s) {
        int idx = (w * 4 + s) * 64 + lane;
        int row = idx >> 3, slot = idx & 7;
        gload_lds16(Vh + (size_t)row * 2048 + (j0 + 64) + (slot ^ (row & 7)) * 8,
                    Vs + (w * 4 + s) * 1024);
      }
    }
  }

  // epilogue: normalize, store bf16 AO. acc rows q = g4*4+r, col d = db*16+lr.
  float lrcp[4];
  #pragma unroll
  for (int r = 0; r < 4; ++r) lrcp[r] = 1.f / __shfl(l_st, g4 * 4 + r, 64);
  #pragma unroll
  for (int db = 0; db < 8; ++db)
    #pragma unroll
    for (int r = 0; r < 4; ++r)
      AO[(size_t)(q0 + w * 16 + g4 * 4 + r) * 2048 + h * 128 + db * 16 + lr] =
          f2bf(acc_o[db][r] * lrcp[r]);
}

// ---------------------------------------------------------------------------
// Launch
// ---------------------------------------------------------------------------
extern "C" void kernel_launch(void* const* d_in, const int* in_sizes, int n_in,
                              void* d_out, int out_size, void* d_ws, size_t ws_size,
                              hipStream_t stream) {
  const float* x         = (const float*)d_in[0];
  const float* Wq        = (const float*)d_in[1];
  const float* Wk        = (const float*)d_in[2];
  const float* Wv        = (const float*)d_in[3];
  const float* Wo        = (const float*)d_in[4];
  const float* pol_dir   = (const float*)d_in[5];
  const float* pol_WA    = (const float*)d_in[6];
  const float* pol_WB    = (const float*)d_in[7];
  const float* pol_gate  = (const float*)d_in[8];
  const float* gtp_gamma = (const float*)d_in[9];
  float* out = (float*)d_out;

  char* ws = (char*)d_ws;
  short* Qb   = (short*)(ws);                    // 2048x2048 bf16 = 8 MB
  short* Kb   = (short*)(ws + 8388608);          // 2048x512  bf16 = 2 MB
  short* Vtb  = (short*)(ws + 10485760);         // 512x2048  bf16 = 2 MB (V^T)
  short* Ab   = (short*)(ws + 12582912);         // 2048x32   bf16 = 128 KB
  short* Bb   = (short*)(ws + 12713984);         // 2048x32   bf16 = 128 KB
  short* Wot  = (short*)(ws + 12845056);         // 8 MB
  short* Wqt  = (short*)(ws + 21233664);         // 8 MB (reused as AO after qkv)
  short* AO   = Wqt;                             // written by attn (Wqt dead)
  short* Wkt  = (short*)(ws + 29622272);         // 2 MB
  short* Wvt  = (short*)(ws + 31719424);         // 2 MB
  short* WABt = (short*)(ws + 33816576);         // 512 KB
  short* xb   = (short*)(ws + 34340864);         // 8 MB
  // total 42.7 MB

  prep_kernel<<<14464, 256, 0, stream>>>(x, Wq, Wk, Wv, pol_WA, pol_WB, Wo,
                                         xb, Wqt, Wkt, Wvt, WABt, Wot);
  gemm_qkv_kernel<<<784, 256, 0, stream>>>(xb, Wqt, Wkt, Wvt, WABt,
                                           Qb, Kb, Vtb, Ab, Bb);
  ropek_kernel<<<2048, 256, 0, stream>>>(Kb);
  attn_kernel<<<dim3(16, 32), 256, 0, stream>>>(Qb, Kb, Vtb, Ab, Bb,
                                                pol_dir, pol_gate, gtp_gamma, AO);
  gemm_out_kernel<<<512, 256, 0, stream>>>(AO, Wot, out);
}